// Round 8
// baseline (1249.793 us; speedup 1.0000x reference)
//
#include <hip/hip_runtime.h>
#include <cstdint>
#include <cstddef>

#define D 128
#define RR 8

typedef __attribute__((ext_vector_type(8))) short short8;
typedef __attribute__((ext_vector_type(4))) float f32x4;

__device__ inline ushort f2b(float x) {
    union { float f; unsigned u; } v; v.f = x;
    unsigned r = v.u + 0x7fff + ((v.u >> 16) & 1);
    return (ushort)(r >> 16);
}
__device__ inline float b2f(ushort u) {
    union { unsigned u; float f; } v; v.u = ((unsigned)u) << 16; return v.f;
}

// async global->LDS, 16B per lane; LDS dest = wave-uniform base + lane*16
__device__ inline void gload_lds16(const ushort* g, ushort* l) {
    __builtin_amdgcn_global_load_lds(
        (const __attribute__((address_space(1))) unsigned int*)g,
        (__attribute__((address_space(3))) unsigned int*)l, 16, 0, 0);
}

// ---------------------------------------------------------------------------
// FUSED RGCN layer: hn = relu([Agg | Hc] @ bigBT + bias), Agg NEVER
// materialized.  Per block (128 rows x 128 cols), 9 K-tiles of 128:
//   r<8 : As tile = per-(node,r) mean of Hc rows, computed by 16-lane groups
//         from CSR, ds_written with 16-group XOR swizzle (round-0 pattern).
//   r=8 : As tile = Hc rows direct, global_load_lds w/ pre-swizzled source.
// B staged in 64-wide async halves, issued BEFORE the gather (loads hide
// under gather latency).  Saves 205 MB Agg write + 205 MB A read per layer.
// LDS 48 KB -> 3 blocks/CU.
// ---------------------------------------------------------------------------
__global__ __launch_bounds__(256, 3) void rgcn_fused(
    const ushort* __restrict__ Hc,
    const int* __restrict__ acsr, const int* __restrict__ aoff,
    const int* __restrict__ cnt,
    const ushort* __restrict__ BT,        // [128][1152]
    const float* __restrict__ bias,
    float* __restrict__ hn, int M)
{
    __shared__ ushort As[128 * 128];      // 32 KB, one 128-wide K-tile
    __shared__ ushort Bs[128 * 64];       // 16 KB, 64-wide half tile
    const int tid = threadIdx.x;
    const int m0 = blockIdx.x * 128;

    const int w = tid >> 6, lane = tid & 63;
    const int wm = (w & 1) * 64, wn = (w >> 1) * 64;
    const int l15 = lane & 15, quad = lane >> 4;

    // B staging ptrs: 64-wide half, 8 groups/row, slot gi = w*256+it*64+lane
    const ushort* bp[4];
#pragma unroll
    for (int it = 0; it < 4; it++) {
        int gi = w * 256 + it * 64 + lane;
        int row = gi >> 3, g = gi & 7;
        int cg = g ^ (row & 7);
        bp[it] = BT + (size_t)row * 1152 + (cg << 3);
    }
    // root-tile As staging ptrs: 128-wide, 16 groups/row, slot gi = w*512+it*64+lane
    const ushort* hp[8];
#pragma unroll
    for (int it = 0; it < 8; it++) {
        int gi = w * 512 + it * 64 + lane;
        int row = gi >> 4, g = gi & 15;
        int cg = g ^ (row & 15);
        int gr = m0 + row; if (gr > M - 1) gr = M - 1;
        hp[it] = Hc + (size_t)gr * 128 + (cg << 3);
    }

    // gather-phase ids: 16 lanes per node, lane gl owns features [gl*8, gl*8+8)
    const int gl = tid & 15;
    const int gn0 = tid >> 4;
    const ushort* hb = Hc + gl * 8;

    f32x4 acc[4][4];
    const f32x4 z4 = {0.f, 0.f, 0.f, 0.f};
#pragma unroll
    for (int i = 0; i < 4; i++)
#pragma unroll
        for (int j = 0; j < 4; j++) acc[i][j] = z4;

    for (int r = 0; r < 9; r++) {
        // issue B half-0 async FIRST (hides under gather latency)
#pragma unroll
        for (int it = 0; it < 4; it++)
            gload_lds16(bp[it] + r * 128, Bs + w * 2048 + it * 512);

        if (r < 8) {
            // gather As tile for relation r: 8 passes x 16 nodes
            for (int pass = 0; pass < 8; pass++) {
                const int nn = pass * 16 + gn0;
                int n = m0 + nn; if (n > M - 1) n = M - 1;   // clamp (not stored)
                const int seg = n * RR + r;
                const int st = aoff[seg];
                const int c = cnt[seg];
                float a[8];
#pragma unroll
                for (int j = 0; j < 8; j++) a[j] = 0.f;
                int i = 0;
                for (; i + 4 <= c; i += 4) {
                    int s0 = acsr[st + i],     s1 = acsr[st + i + 1];
                    int s2 = acsr[st + i + 2], s3 = acsr[st + i + 3];
                    short8 y0 = *(const short8*)(hb + (size_t)s0 * 128);
                    short8 y1 = *(const short8*)(hb + (size_t)s1 * 128);
                    short8 y2 = *(const short8*)(hb + (size_t)s2 * 128);
                    short8 y3 = *(const short8*)(hb + (size_t)s3 * 128);
#pragma unroll
                    for (int j = 0; j < 8; j++)
                        a[j] += (b2f((ushort)y0[j]) + b2f((ushort)y1[j]))
                              + (b2f((ushort)y2[j]) + b2f((ushort)y3[j]));
                }
                if (i + 2 <= c) {
                    int s0 = acsr[st + i], s1 = acsr[st + i + 1];
                    short8 y0 = *(const short8*)(hb + (size_t)s0 * 128);
                    short8 y1 = *(const short8*)(hb + (size_t)s1 * 128);
#pragma unroll
                    for (int j = 0; j < 8; j++)
                        a[j] += b2f((ushort)y0[j]) + b2f((ushort)y1[j]);
                    i += 2;
                }
                if (i < c) {
                    int s0 = acsr[st + i];
                    short8 y0 = *(const short8*)(hb + (size_t)s0 * 128);
#pragma unroll
                    for (int j = 0; j < 8; j++)
                        a[j] += b2f((ushort)y0[j]);
                }
                short8 outv = {0, 0, 0, 0, 0, 0, 0, 0};
                if (c > 0) {
                    float inv = 1.f / (float)c;
#pragma unroll
                    for (int j = 0; j < 8; j++) outv[j] = (short)f2b(a[j] * inv);
                }
                *(short8*)(&As[nn * 128 + ((gl ^ (nn & 15)) << 3)]) = outv;
            }
        } else {
            // root tile: direct-stage Hc rows (pre-swizzled source)
#pragma unroll
            for (int it = 0; it < 8; it++)
                gload_lds16(hp[it], As + w * 4096 + it * 512);
        }
        __syncthreads();   // drains ds_writes + async loads (compiler waitcnt)

#pragma unroll
        for (int h = 0; h < 2; h++) {
            if (h == 1) {
                __syncthreads();           // MFMA half-0 reads done
#pragma unroll
                for (int it = 0; it < 4; it++)
                    gload_lds16(bp[it] + r * 128 + 64, Bs + w * 2048 + it * 512);
                __syncthreads();           // Bs half-1 ready
            }
#pragma unroll
            for (int s = 0; s < 2; s++) {
                const int g0a = ((h * 64 + s * 32) >> 3) + quad;   // 0..15
                const int g0b = ((s * 32) >> 3) + quad;            // 0..7
                short8 af[4], bfr[4];
#pragma unroll
                for (int i = 0; i < 4; i++) {
                    int row = wm + i * 16 + l15;
                    af[i] = *(const short8*)(&As[row * 128 + ((g0a ^ (row & 15)) << 3)]);
                }
#pragma unroll
                for (int j = 0; j < 4; j++) {
                    int row = wn + j * 16 + l15;
                    bfr[j] = *(const short8*)(&Bs[row * 64 + ((g0b ^ (row & 7)) << 3)]);
                }
#pragma unroll
                for (int i = 0; i < 4; i++)
#pragma unroll
                    for (int j = 0; j < 4; j++)
                        acc[i][j] = __builtin_amdgcn_mfma_f32_16x16x32_bf16(
                            af[i], bfr[j], acc[i][j], 0, 0, 0);
            }
        }
        __syncthreads();   // protect As/Bs before next tile
    }

    // epilogue: bias + relu, fp32 store (ncol = 128)
#pragma unroll
    for (int i = 0; i < 4; i++) {
#pragma unroll
        for (int q = 0; q < 4; q++) {
            int gm = m0 + wm + i * 16 + quad * 4 + q;
            if (gm >= M) continue;
#pragma unroll
            for (int j = 0; j < 4; j++) {
                int gn = wn + j * 16 + l15;
                float v = acc[i][j][q] + bias[gn];
                v = v > 0.f ? v : 0.f;
                hn[(size_t)gm * 128 + gn] = v;
            }
        }
    }
}

// ---------------------------------------------------------------------------
// generic bf16 MFMA GEMM (proj / out layers) — unchanged, measured good
// ---------------------------------------------------------------------------
template<bool BIAS, bool RELU, bool STF, bool STB>
__global__ __launch_bounds__(256, 4) void gemm_bf16(
    const ushort* __restrict__ A0, int lda0, int k0steps,
    const ushort* __restrict__ A1, int lda1,
    const ushort* __restrict__ BT, int ktiles,
    const float* __restrict__ bias, float* __restrict__ Cf, int ldcf,
    ushort* __restrict__ Cb, int ldcb, int M, int ncol)
{
    __shared__ ushort As[128 * 64];
    __shared__ ushort Bs[128 * 64];
    const int tid = threadIdx.x;
    const int m0 = blockIdx.x * 128;
    const int ldb = ktiles * 128;
    const int ksteps = ktiles * 2;          // BK = 64

    const int w = tid >> 6, lane = tid & 63;
    const int wm = (w & 1) * 64, wn = (w >> 1) * 64;
    const int l15 = lane & 15, quad = lane >> 4;

    const ushort* a0p[4];
    const ushort* a1p[4];
    const ushort* bp[4];
#pragma unroll
    for (int it = 0; it < 4; it++) {
        int gi = w * 256 + it * 64 + lane;
        int row = gi >> 3, g = gi & 7;
        int cg = g ^ (row & 7);
        int gr = m0 + row; if (gr > M - 1) gr = M - 1;   // clamp tail
        a0p[it] = A0 + (size_t)gr * lda0 + (cg << 3);
        a1p[it] = A1 + (size_t)gr * lda1 + (cg << 3);
        bp[it]  = BT + (size_t)row * ldb + (cg << 3);
    }

    f32x4 acc[4][4];
    const f32x4 z4 = {0.f, 0.f, 0.f, 0.f};
#pragma unroll
    for (int i = 0; i < 4; i++)
#pragma unroll
        for (int j = 0; j < 4; j++) acc[i][j] = z4;

    for (int kt = 0; kt < ksteps; kt++) {
        const int ko = kt * 64;
        if (kt < k0steps) {
#pragma unroll
            for (int it = 0; it < 4; it++)
                gload_lds16(a0p[it] + ko, As + w * 2048 + it * 512);
        } else {
            const int ko1 = (kt - k0steps) * 64;
#pragma unroll
            for (int it = 0; it < 4; it++)
                gload_lds16(a1p[it] + ko1, As + w * 2048 + it * 512);
        }
#pragma unroll
        for (int it = 0; it < 4; it++)
            gload_lds16(bp[it] + ko, Bs + w * 2048 + it * 512);
        __syncthreads();

#pragma unroll
        for (int ks = 0; ks < 64; ks += 32) {
            const int q0 = (ks >> 3) + quad;
            short8 af[4], bfr[4];
#pragma unroll
            for (int i = 0; i < 4; i++) {
                int row = wm + i * 16 + l15;
                af[i] = *(const short8*)(&As[row * 64 + ((q0 ^ (row & 7)) << 3)]);
            }
#pragma unroll
            for (int j = 0; j < 4; j++) {
                int row = wn + j * 16 + l15;
                bfr[j] = *(const short8*)(&Bs[row * 64 + ((q0 ^ (row & 7)) << 3)]);
            }
#pragma unroll
            for (int i = 0; i < 4; i++)
#pragma unroll
                for (int j = 0; j < 4; j++)
                    acc[i][j] = __builtin_amdgcn_mfma_f32_16x16x32_bf16(
                        af[i], bfr[j], acc[i][j], 0, 0, 0);
        }
        __syncthreads();
    }

#pragma unroll
    for (int i = 0; i < 4; i++) {
#pragma unroll
        for (int q = 0; q < 4; q++) {
            int gm = m0 + wm + i * 16 + quad * 4 + q;
            if (gm >= M) continue;
#pragma unroll
            for (int j = 0; j < 4; j++) {
                int gn = wn + j * 16 + l15;
                if (gn >= ncol) continue;
                float v = acc[i][j][q];
                if (BIAS) v += bias[gn];
                if (RELU) v = v > 0.f ? v : 0.f;
                if (STF) Cf[(size_t)gm * ldcf + gn] = v;
                if (STB) Cb[(size_t)gm * ldcb + gn] = f2b(v);
            }
        }
    }
}

// ---------------------------------------------------------------------------
// bigBT[f][c]: c<1024 -> W_{c>>7}[c&127][f];  c>=1024 -> root[c-1024][f]
// ---------------------------------------------------------------------------
__global__ void build_bigBT(const float* __restrict__ basis,
                            const float* __restrict__ comp,
                            const float* __restrict__ root,
                            ushort* __restrict__ BT)
{
    int i = blockIdx.x * 256 + threadIdx.x;
    if (i >= 128 * 1152) return;
    int f = i / 1152, c = i - f * 1152;
    float a;
    if (c < 1024) {
        int r = c >> 7, d = c & 127;
        a = 0.f;
#pragma unroll
        for (int b = 0; b < 4; b++)
            a += comp[r * 4 + b] * basis[(b * 128 + d) * 128 + f];
    } else {
        a = root[(c - 1024) * 128 + f];
    }
    BT[i] = f2b(a);
}

// out[f*128+k] = bf16(in[k*cols+f]) for f<cols else 0   (in: [128][cols])
__global__ void transpose_pad(const float* __restrict__ in, ushort* __restrict__ out,
                              int cols)
{
    int i = blockIdx.x * 256 + threadIdx.x;
    if (i >= 128 * 128) return;
    int k = i & 127, f = i >> 7;
    out[i] = (f < cols) ? f2b(in[k * cols + f]) : (ushort)0;
}

// x [N][128] fp32 -> compact bf16 Hc [N][128]
__global__ void cast_x(const float* __restrict__ in, ushort* __restrict__ Hc, int total4)
{
    int i = blockIdx.x * 256 + threadIdx.x;
    if (i >= total4) return;
    float4 v = ((const float4*)in)[i];
    ushort4 o = { f2b(v.x), f2b(v.y), f2b(v.z), f2b(v.w) };
    *(ushort4*)(Hc + (size_t)i * 4) = o;
}

// ---------------------------------------------------------------------------
// count pass recording each edge's slot (atomicAdd return).  int4 loads/stores
// (round-7 measured: 193 -> 138 us).
// ---------------------------------------------------------------------------
__global__ void count_slot(const int* __restrict__ src, const int* __restrict__ dst,
                           const int* __restrict__ et, int* __restrict__ cnt,
                           int* __restrict__ deg, int* __restrict__ slotA,
                           int* __restrict__ slotG, int E)
{
    int t = blockIdx.x * 256 + threadIdx.x;
    int e0 = t * 4;
    if (e0 + 4 <= E) {
        int4 s4 = ((const int4*)src)[t];
        int4 d4 = ((const int4*)dst)[t];
        int4 t4 = ((const int4*)et)[t];
        int4 sa, sg;
        sa.x = atomicAdd(&cnt[d4.x * RR + t4.x], 1);
        sa.y = atomicAdd(&cnt[d4.y * RR + t4.y], 1);
        sa.z = atomicAdd(&cnt[d4.z * RR + t4.z], 1);
        sa.w = atomicAdd(&cnt[d4.w * RR + t4.w], 1);
        sg.x = atomicAdd(&deg[s4.x], 1);
        sg.y = atomicAdd(&deg[s4.y], 1);
        sg.z = atomicAdd(&deg[s4.z], 1);
        sg.w = atomicAdd(&deg[s4.w], 1);
        ((int4*)slotA)[t] = sa;
        ((int4*)slotG)[t] = sg;
    } else {
        for (int e = e0; e < E; e++) {
            slotA[e] = atomicAdd(&cnt[dst[e] * RR + et[e]], 1);
            slotG[e] = atomicAdd(&deg[src[e]], 1);
        }
    }
}

// ---------------------------------------------------------------------------
// 3-phase exclusive scan (1024 elements per block)
// ---------------------------------------------------------------------------
__global__ void scan1(const int* __restrict__ in, int* __restrict__ bsum, int n)
{
    __shared__ int s[256];
    const int b = blockIdx.x, t = threadIdx.x;
    const int base = b * 1024;
    int v = 0;
#pragma unroll
    for (int i = 0; i < 4; i++) {
        int idx = base + t * 4 + i;
        if (idx < n) v += in[idx];
    }
    s[t] = v; __syncthreads();
    for (int off = 128; off > 0; off >>= 1) {
        if (t < off) s[t] += s[t + off];
        __syncthreads();
    }
    if (t == 0) bsum[b] = s[0];
}

__global__ void scan_top(int* __restrict__ bsum, int nb)
{
    __shared__ int s[1024];
    const int t = threadIdx.x;
    int v = (t < nb) ? bsum[t] : 0;
    s[t] = v; __syncthreads();
    for (int off = 1; off < 1024; off <<= 1) {
        int x = (t >= off) ? s[t - off] : 0;
        __syncthreads();
        s[t] += x;
        __syncthreads();
    }
    if (t < nb) bsum[t] = s[t] - v;   // exclusive
}

__global__ void scan2(const int* __restrict__ in, const int* __restrict__ bsum,
                      int* __restrict__ out, int n)
{
    __shared__ int s[256];
    const int b = blockIdx.x, t = threadIdx.x;
    const int base = b * 1024;
    int loc[4];
    int v = 0;
#pragma unroll
    for (int i = 0; i < 4; i++) {
        int idx = base + t * 4 + i;
        int x = (idx < n) ? in[idx] : 0;
        loc[i] = v; v += x;
    }
    s[t] = v; __syncthreads();
    for (int off = 1; off < 256; off <<= 1) {
        int x = (t >= off) ? s[t - off] : 0;
        __syncthreads();
        s[t] += x;
        __syncthreads();
    }
    const int add = bsum[b] + (s[t] - v);
#pragma unroll
    for (int i = 0; i < 4; i++) {
        int idx = base + t * 4 + i;
        if (idx < n) out[idx] = add + loc[i];
    }
}

// ---------------------------------------------------------------------------
// fill pass with NO atomics: position = scanned offset + pre-recorded slot.
// ---------------------------------------------------------------------------
__global__ void fill_scatter(const int* __restrict__ src, const int* __restrict__ dst,
                             const int* __restrict__ et,
                             const int* __restrict__ aoff, const int* __restrict__ goff,
                             const int* __restrict__ slotA, const int* __restrict__ slotG,
                             int* __restrict__ acsr, int* __restrict__ gcsr, int E)
{
    int t = blockIdx.x * 256 + threadIdx.x;
    int e0 = t * 4;
    if (e0 + 4 <= E) {
        int4 s4 = ((const int4*)src)[t];
        int4 d4 = ((const int4*)dst)[t];
        int4 t4 = ((const int4*)et)[t];
        int4 sa = ((const int4*)slotA)[t];
        int4 sg = ((const int4*)slotG)[t];
        acsr[aoff[d4.x * RR + t4.x] + sa.x] = s4.x;
        acsr[aoff[d4.y * RR + t4.y] + sa.y] = s4.y;
        acsr[aoff[d4.z * RR + t4.z] + sa.z] = s4.z;
        acsr[aoff[d4.w * RR + t4.w] + sa.w] = s4.w;
        gcsr[goff[s4.x] + sg.x] = d4.x;
        gcsr[goff[s4.y] + sg.y] = d4.y;
        gcsr[goff[s4.z] + sg.z] = d4.z;
        gcsr[goff[s4.w] + sg.w] = d4.w;
    } else {
        for (int e = e0; e < E; e++) {
            int s0 = src[e], d0 = dst[e];
            acsr[aoff[d0 * RR + et[e]] + slotA[e]] = s0;
            gcsr[goff[s0] + slotG[e]] = d0;
        }
    }
}

// ---------------------------------------------------------------------------
// gate gather: 16-lane group per node, short8 row loads (round-6 measured
// form: 4-wide head + pairwise + scalar tails, plain loads).
// TAUb[n] = bf16(tanh( mean_out (h[n]-h[dst])^2 ))
// ---------------------------------------------------------------------------
__global__ __launch_bounds__(256) void gate_gather(
    const ushort* __restrict__ Hc, const int* __restrict__ gcsr,
    const int* __restrict__ goff, const int* __restrict__ deg,
    ushort* __restrict__ TAUb, int N)
{
    const int g = threadIdx.x >> 4, lane = threadIdx.x & 15;
    const int n = blockIdx.x * 16 + g;
    if (n >= N) return;
    const int start = goff[n];
    const int c = deg[n];
    const ushort* hbase = Hc + lane * 8;
    const short8 a8 = *(const short8*)(hbase + (size_t)n * 128);
    float av[8];
#pragma unroll
    for (int j = 0; j < 8; j++) av[j] = b2f((ushort)a8[j]);
    float acc[8];
#pragma unroll
    for (int j = 0; j < 8; j++) acc[j] = 0.f;

    int i = 0;
    for (; i + 4 <= c; i += 4) {
        int d0 = gcsr[start + i],     d1 = gcsr[start + i + 1];
        int d2 = gcsr[start + i + 2], d3 = gcsr[start + i + 3];
        short8 b0 = *(const short8*)(hbase + (size_t)d0 * 128);
        short8 b1 = *(const short8*)(hbase + (size_t)d1 * 128);
        short8 b2 = *(const short8*)(hbase + (size_t)d2 * 128);
        short8 b3 = *(const short8*)(hbase + (size_t)d3 * 128);
#pragma unroll
        for (int j = 0; j < 8; j++) {
            float dx0 = av[j] - b2f((ushort)b0[j]);
            float dx1 = av[j] - b2f((ushort)b1[j]);
            float dx2 = av[j] - b2f((ushort)b2[j]);
            float dx3 = av[j] - b2f((ushort)b3[j]);
            acc[j] += dx0 * dx0 + dx1 * dx1 + dx2 * dx2 + dx3 * dx3;
        }
    }
    if (i + 2 <= c) {
        int d0 = gcsr[start + i], d1 = gcsr[start + i + 1];
        short8 b0 = *(const short8*)(hbase + (size_t)d0 * 128);
        short8 b1 = *(const short8*)(hbase + (size_t)d1 * 128);
#pragma unroll
        for (int j = 0; j < 8; j++) {
            float dx0 = av[j] - b2f((ushort)b0[j]);
            float dx1 = av[j] - b2f((ushort)b1[j]);
            acc[j] += dx0 * dx0 + dx1 * dx1;
        }
        i += 2;
    }
    if (i < c) {
        int d0 = gcsr[start + i];
        short8 b0 = *(const short8*)(hbase + (size_t)d0 * 128);
#pragma unroll
        for (int j = 0; j < 8; j++) {
            float dx0 = av[j] - b2f((ushort)b0[j]);
            acc[j] += dx0 * dx0;
        }
    }
    const float inv = (c > 0) ? (1.f / (float)c) : 1.f;
    short8 t;
#pragma unroll
    for (int j = 0; j < 8; j++) t[j] = (short)f2b(tanhf(acc[j] * inv));
    *(short8*)(TAUb + (size_t)n * D + lane * 8) = t;
}

// ---------------------------------------------------------------------------
// h_next = (1-tau)*h + tau*hn  (hn already relu'd by GEMM epilogue);
// writes fp32 hn and compact bf16 Hc
// ---------------------------------------------------------------------------
__global__ void finalize(const float* __restrict__ hp, float* __restrict__ hn,
                         const ushort* __restrict__ TAUb, ushort* __restrict__ Hc,
                         int total4)
{
    int idx = blockIdx.x * 256 + threadIdx.x;
    if (idx >= total4) return;
    const float4 p = ((const float4*)hp)[idx];
    const float4 a = ((const float4*)hn)[idx];
    const ushort4 t4 = ((const ushort4*)TAUb)[idx];
    float4 o;
    o.x = p.x + b2f(t4.x) * (a.x - p.x);
    o.y = p.y + b2f(t4.y) * (a.y - p.y);
    o.z = p.z + b2f(t4.z) * (a.z - p.z);
    o.w = p.w + b2f(t4.w) * (a.w - p.w);
    ((float4*)hn)[idx] = o;
    ushort4 ob = { f2b(o.x), f2b(o.y), f2b(o.z), f2b(o.w) };
    *(ushort4*)(Hc + (size_t)idx * 4) = ob;
}

// ---------------------------------------------------------------------------
extern "C" void kernel_launch(void* const* d_in, const int* in_sizes, int n_in,
                              void* d_out, int out_size, void* d_ws, size_t ws_size,
                              hipStream_t stream)
{
    const float* x      = (const float*)d_in[0];
    const int*   src    = (const int*)  d_in[1];
    const int*   dst    = (const int*)  d_in[2];
    const int*   etyp   = (const int*)  d_in[3];
    const float* projW  = (const float*)d_in[4];
    const float* projb  = (const float*)d_in[5];
    const float* basis1 = (const float*)d_in[6];
    const float* comp1  = (const float*)d_in[7];
    const float* root1  = (const float*)d_in[8];
    const float* bias1  = (const float*)d_in[9];
    const float* basis2 = (const float*)d_in[10];
    const float* comp2  = (const float*)d_in[11];
    const float* root2  = (const float*)d_in[12];
    const float* bias2  = (const float*)d_in[13];
    const float* outW   = (const float*)d_in[14];
    const float* outb   = (const float*)d_in[15];

    const int N    = in_sizes[0] / D;
    const int E    = in_sizes[1];
    const int OUTD = in_sizes[15];

    float* out  = (float*)d_out;
    float* lat0 = out + (size_t)N * OUTD;
    float* lat1 = lat0 + (size_t)N * D;
    float* lat2 = lat1 + (size_t)N * D;

    // ---- workspace layout (Agg removed — never materialized) ----
    char* p = (char*)d_ws;
    ushort* Hc    = (ushort*)p;  p += (size_t)N * 128 * 2;    // [N][128] bf16
    ushort* TAUb  = (ushort*)p;  p += (size_t)N * D * 2;
    ushort* projWT = (ushort*)p; p += 16384 * 2;
    ushort* outWT  = (ushort*)p; p += 16384 * 2;
    ushort* bigBT1 = (ushort*)p; p += (size_t)128 * 1152 * 2;
    ushort* bigBT2 = (ushort*)p; p += (size_t)128 * 1152 * 2;
    int* cnt_i  = (int*)p;       p += (size_t)N * RR * 4;
    int* deg_i  = (int*)p;       p += (size_t)N * 4;
    int* aoff   = (int*)p;       p += (size_t)N * RR * 4;
    int* goff   = (int*)p;       p += (size_t)N * 4;
    int* slotA  = (int*)p;       p += (size_t)E * 4;
    int* slotG  = (int*)p;       p += (size_t)E * 4;
    int* acsr   = (int*)p;       p += (size_t)E * 4;
    int* gcsr   = (int*)p;       p += (size_t)E * 4;
    int* bsum   = (int*)p;       p += 4096;

    if ((size_t)(p - (char*)d_ws) > ws_size) return;  // fails loudly

    // zero counters (cnt_i, deg_i contiguous)
    hipMemsetAsync(cnt_i, 0, sizeof(int) * ((size_t)N * RR + N), stream);

    // weight prep
    build_bigBT<<<(128 * 1152 + 255) / 256, 256, 0, stream>>>(basis1, comp1, root1, bigBT1);
    build_bigBT<<<(128 * 1152 + 255) / 256, 256, 0, stream>>>(basis2, comp2, root2, bigBT2);
    transpose_pad<<<64, 256, 0, stream>>>(projW, projWT, 128);
    transpose_pad<<<64, 256, 0, stream>>>(outW, outWT, OUTD);

    cast_x<<<(N * 32 + 255) / 256, 256, 0, stream>>>(x, Hc, N * 32);

    count_slot<<<(E / 4 + 255) / 256, 256, 0, stream>>>(
        src, dst, etyp, cnt_i, deg_i, slotA, slotG, E);

    {   // exclusive scans -> CSR offsets
        int n1 = N * RR, nb1 = (n1 + 1023) / 1024;
        scan1<<<nb1, 256, 0, stream>>>(cnt_i, bsum, n1);
        scan_top<<<1, 1024, 0, stream>>>(bsum, nb1);
        scan2<<<nb1, 256, 0, stream>>>(cnt_i, bsum, aoff, n1);
        int nb2 = (N + 1023) / 1024;
        scan1<<<nb2, 256, 0, stream>>>(deg_i, bsum, N);
        scan_top<<<1, 1024, 0, stream>>>(bsum, nb2);
        scan2<<<nb2, 256, 0, stream>>>(deg_i, bsum, goff, N);
    }

    fill_scatter<<<(E / 4 + 255) / 256, 256, 0, stream>>>(
        src, dst, etyp, aoff, goff, slotA, slotG, acsr, gcsr, E);

    const int mb = (N + 127) / 128;
    const int nodeblocks16 = (N + 15) / 16;

    // proj: lat0 = relu(x @ projW + projb); bf16 -> Hc (in-place safe)
    gemm_bf16<true, true, true, true><<<mb, 256, 0, stream>>>(
        Hc, 128, 2, Hc, 128, projWT, 1, projb, lat0, 128, Hc, 128, N, 128);

    const ushort* bigBT[2] = {bigBT1, bigBT2};
    const float* biases[2] = {bias1, bias2};
    float* lats[3]         = {lat0, lat1, lat2};

    for (int l = 0; l < 2; l++) {
        float* hn = lats[l + 1];

        gate_gather<<<nodeblocks16, 256, 0, stream>>>(Hc, gcsr, goff, deg_i, TAUb, N);

        // hn = relu([Agg | Hc] @ [W_1..W_8; root] + bias), Agg fused
        rgcn_fused<<<mb, 256, 0, stream>>>(
            Hc, acsr, aoff, cnt_i, bigBT[l], biases[l], hn, N);

        finalize<<<(N * 32 + 255) / 256, 256, 0, stream>>>(
            lats[l], hn, TAUb, Hc, N * 32);
    }

    // out = lat2 @ outW + outb
    gemm_bf16<true, false, true, false><<<mb, 256, 0, stream>>>(
        Hc, 128, 2, Hc, 128, outWT, 1, outb, out, OUTD, nullptr, 0, N, OUTD);
}

// Round 9
// 1020.473 us; speedup vs baseline: 1.2247x; 1.2247x over previous
//
#include <hip/hip_runtime.h>
#include <cstdint>
#include <cstddef>

#define D 128
#define RR 8

typedef __attribute__((ext_vector_type(8))) short short8;
typedef __attribute__((ext_vector_type(4))) float f32x4;

__device__ inline ushort f2b(float x) {
    union { float f; unsigned u; } v; v.f = x;
    unsigned r = v.u + 0x7fff + ((v.u >> 16) & 1);
    return (ushort)(r >> 16);
}
__device__ inline float b2f(ushort u) {
    union { unsigned u; float f; } v; v.u = ((unsigned)u) << 16; return v.f;
}

// async global->LDS, 16B per lane; LDS dest = wave-uniform base + lane*16
__device__ inline void gload_lds16(const ushort* g, ushort* l) {
    __builtin_amdgcn_global_load_lds(
        (const __attribute__((address_space(1))) unsigned int*)g,
        (__attribute__((address_space(3))) unsigned int*)l, 16, 0, 0);
}

// ---------------------------------------------------------------------------
// bf16 MFMA GEMM with SPLIT A: C[M, ncol] = [A0 | A1] @ B (+bias) (+relu)
// (round-5/6 measured-good form)
// ---------------------------------------------------------------------------
template<bool BIAS, bool RELU, bool STF, bool STB>
__global__ __launch_bounds__(256, 4) void gemm_bf16(
    const ushort* __restrict__ A0, int lda0, int k0steps,
    const ushort* __restrict__ A1, int lda1,
    const ushort* __restrict__ BT, int ktiles,
    const float* __restrict__ bias, float* __restrict__ Cf, int ldcf,
    ushort* __restrict__ Cb, int ldcb, int M, int ncol)
{
    __shared__ ushort As[128 * 64];
    __shared__ ushort Bs[128 * 64];
    const int tid = threadIdx.x;
    const int m0 = blockIdx.x * 128;
    const int ldb = ktiles * 128;
    const int ksteps = ktiles * 2;          // BK = 64

    const int w = tid >> 6, lane = tid & 63;
    const int wm = (w & 1) * 64, wn = (w >> 1) * 64;
    const int l15 = lane & 15, quad = lane >> 4;

    const ushort* a0p[4];
    const ushort* a1p[4];
    const ushort* bp[4];
#pragma unroll
    for (int it = 0; it < 4; it++) {
        int gi = w * 256 + it * 64 + lane;
        int row = gi >> 3, g = gi & 7;
        int cg = g ^ (row & 7);
        int gr = m0 + row; if (gr > M - 1) gr = M - 1;   // clamp tail
        a0p[it] = A0 + (size_t)gr * lda0 + (cg << 3);
        a1p[it] = A1 + (size_t)gr * lda1 + (cg << 3);
        bp[it]  = BT + (size_t)row * ldb + (cg << 3);    // B rows 0..127 always valid
    }

    f32x4 acc[4][4];
    const f32x4 z4 = {0.f, 0.f, 0.f, 0.f};
#pragma unroll
    for (int i = 0; i < 4; i++)
#pragma unroll
        for (int j = 0; j < 4; j++) acc[i][j] = z4;

    for (int kt = 0; kt < ksteps; kt++) {
        const int ko = kt * 64;
        if (kt < k0steps) {
#pragma unroll
            for (int it = 0; it < 4; it++)
                gload_lds16(a0p[it] + ko, As + w * 2048 + it * 512);
        } else {
            const int ko1 = (kt - k0steps) * 64;
#pragma unroll
            for (int it = 0; it < 4; it++)
                gload_lds16(a1p[it] + ko1, As + w * 2048 + it * 512);
        }
#pragma unroll
        for (int it = 0; it < 4; it++)
            gload_lds16(bp[it] + ko, Bs + w * 2048 + it * 512);
        __syncthreads();   // compiler emits vmcnt(0) drain before barrier

#pragma unroll
        for (int ks = 0; ks < 64; ks += 32) {
            const int q0 = (ks >> 3) + quad;        // k-group 0..7
            short8 af[4], bfr[4];
#pragma unroll
            for (int i = 0; i < 4; i++) {
                int row = wm + i * 16 + l15;
                af[i] = *(const short8*)(&As[row * 64 + ((q0 ^ (row & 7)) << 3)]);
            }
#pragma unroll
            for (int j = 0; j < 4; j++) {
                int row = wn + j * 16 + l15;
                bfr[j] = *(const short8*)(&Bs[row * 64 + ((q0 ^ (row & 7)) << 3)]);
            }
#pragma unroll
            for (int i = 0; i < 4; i++)
#pragma unroll
                for (int j = 0; j < 4; j++)
                    acc[i][j] = __builtin_amdgcn_mfma_f32_16x16x32_bf16(
                        af[i], bfr[j], acc[i][j], 0, 0, 0);
        }
        __syncthreads();
    }

    // epilogue: C[m=quad*4+q][n=l15] per 16x16 frag
#pragma unroll
    for (int i = 0; i < 4; i++) {
#pragma unroll
        for (int q = 0; q < 4; q++) {
            int gm = m0 + wm + i * 16 + quad * 4 + q;
            if (gm >= M) continue;
#pragma unroll
            for (int j = 0; j < 4; j++) {
                int gn = wn + j * 16 + l15;
                if (gn >= ncol) continue;
                float v = acc[i][j][q];
                if (BIAS) v += bias[gn];
                if (RELU) v = v > 0.f ? v : 0.f;
                if (STF) Cf[(size_t)gm * ldcf + gn] = v;
                if (STB) Cb[(size_t)gm * ldcb + gn] = f2b(v);
            }
        }
    }
}

// ---------------------------------------------------------------------------
// bigBT[f][c]: c<1024 -> W_{c>>7}[c&127][f];  c>=1024 -> root[c-1024][f]
// ---------------------------------------------------------------------------
__global__ void build_bigBT(const float* __restrict__ basis,
                            const float* __restrict__ comp,
                            const float* __restrict__ root,
                            ushort* __restrict__ BT)
{
    int i = blockIdx.x * 256 + threadIdx.x;
    if (i >= 128 * 1152) return;
    int f = i / 1152, c = i - f * 1152;
    float a;
    if (c < 1024) {
        int r = c >> 7, d = c & 127;
        a = 0.f;
#pragma unroll
        for (int b = 0; b < 4; b++)
            a += comp[r * 4 + b] * basis[(b * 128 + d) * 128 + f];
    } else {
        a = root[(c - 1024) * 128 + f];
    }
    BT[i] = f2b(a);
}

// out[f*128+k] = bf16(in[k*cols+f]) for f<cols else 0   (in: [128][cols])
__global__ void transpose_pad(const float* __restrict__ in, ushort* __restrict__ out,
                              int cols)
{
    int i = blockIdx.x * 256 + threadIdx.x;
    if (i >= 128 * 128) return;
    int k = i & 127, f = i >> 7;
    out[i] = (f < cols) ? f2b(in[k * cols + f]) : (ushort)0;
}

// x [N][128] fp32 -> compact bf16 Hc [N][128]
__global__ void cast_x(const float* __restrict__ in, ushort* __restrict__ Hc, int total4)
{
    int i = blockIdx.x * 256 + threadIdx.x;
    if (i >= total4) return;
    float4 v = ((const float4*)in)[i];
    ushort4 o = { f2b(v.x), f2b(v.y), f2b(v.z), f2b(v.w) };
    *(ushort4*)(Hc + (size_t)i * 4) = o;
}

// ---------------------------------------------------------------------------
// count pass recording each edge's slot (atomicAdd return).  int4 loads/stores
// (round-7 measured: 193 -> 138 us).
// ---------------------------------------------------------------------------
__global__ void count_slot(const int* __restrict__ src, const int* __restrict__ dst,
                           const int* __restrict__ et, int* __restrict__ cnt,
                           int* __restrict__ deg, int* __restrict__ slotA,
                           int* __restrict__ slotG, int E)
{
    int t = blockIdx.x * 256 + threadIdx.x;
    int e0 = t * 4;
    if (e0 + 4 <= E) {
        int4 s4 = ((const int4*)src)[t];
        int4 d4 = ((const int4*)dst)[t];
        int4 t4 = ((const int4*)et)[t];
        int4 sa, sg;
        sa.x = atomicAdd(&cnt[d4.x * RR + t4.x], 1);
        sa.y = atomicAdd(&cnt[d4.y * RR + t4.y], 1);
        sa.z = atomicAdd(&cnt[d4.z * RR + t4.z], 1);
        sa.w = atomicAdd(&cnt[d4.w * RR + t4.w], 1);
        sg.x = atomicAdd(&deg[s4.x], 1);
        sg.y = atomicAdd(&deg[s4.y], 1);
        sg.z = atomicAdd(&deg[s4.z], 1);
        sg.w = atomicAdd(&deg[s4.w], 1);
        ((int4*)slotA)[t] = sa;
        ((int4*)slotG)[t] = sg;
    } else {
        for (int e = e0; e < E; e++) {
            slotA[e] = atomicAdd(&cnt[dst[e] * RR + et[e]], 1);
            slotG[e] = atomicAdd(&deg[src[e]], 1);
        }
    }
}

// ---------------------------------------------------------------------------
// 3-phase exclusive scan (1024 elements per block)
// ---------------------------------------------------------------------------
__global__ void scan1(const int* __restrict__ in, int* __restrict__ bsum, int n)
{
    __shared__ int s[256];
    const int b = blockIdx.x, t = threadIdx.x;
    const int base = b * 1024;
    int v = 0;
#pragma unroll
    for (int i = 0; i < 4; i++) {
        int idx = base + t * 4 + i;
        if (idx < n) v += in[idx];
    }
    s[t] = v; __syncthreads();
    for (int off = 128; off > 0; off >>= 1) {
        if (t < off) s[t] += s[t + off];
        __syncthreads();
    }
    if (t == 0) bsum[b] = s[0];
}

__global__ void scan_top(int* __restrict__ bsum, int nb)
{
    __shared__ int s[1024];
    const int t = threadIdx.x;
    int v = (t < nb) ? bsum[t] : 0;
    s[t] = v; __syncthreads();
    for (int off = 1; off < 1024; off <<= 1) {
        int x = (t >= off) ? s[t - off] : 0;
        __syncthreads();
        s[t] += x;
        __syncthreads();
    }
    if (t < nb) bsum[t] = s[t] - v;   // exclusive
}

__global__ void scan2(const int* __restrict__ in, const int* __restrict__ bsum,
                      int* __restrict__ out, int n)
{
    __shared__ int s[256];
    const int b = blockIdx.x, t = threadIdx.x;
    const int base = b * 1024;
    int loc[4];
    int v = 0;
#pragma unroll
    for (int i = 0; i < 4; i++) {
        int idx = base + t * 4 + i;
        int x = (idx < n) ? in[idx] : 0;
        loc[i] = v; v += x;
    }
    s[t] = v; __syncthreads();
    for (int off = 1; off < 256; off <<= 1) {
        int x = (t >= off) ? s[t - off] : 0;
        __syncthreads();
        s[t] += x;
        __syncthreads();
    }
    const int add = bsum[b] + (s[t] - v);
#pragma unroll
    for (int i = 0; i < 4; i++) {
        int idx = base + t * 4 + i;
        if (idx < n) out[idx] = add + loc[i];
    }
}

// ---------------------------------------------------------------------------
// fill pass with NO atomics: position = scanned offset + pre-recorded slot.
// int4 edge/slot loads; all chains independent -> full MLP.
// ---------------------------------------------------------------------------
__global__ void fill_scatter(const int* __restrict__ src, const int* __restrict__ dst,
                             const int* __restrict__ et,
                             const int* __restrict__ aoff, const int* __restrict__ goff,
                             const int* __restrict__ slotA, const int* __restrict__ slotG,
                             int* __restrict__ acsr, int* __restrict__ gcsr, int E)
{
    int t = blockIdx.x * 256 + threadIdx.x;
    int e0 = t * 4;
    if (e0 + 4 <= E) {
        int4 s4 = ((const int4*)src)[t];
        int4 d4 = ((const int4*)dst)[t];
        int4 t4 = ((const int4*)et)[t];
        int4 sa = ((const int4*)slotA)[t];
        int4 sg = ((const int4*)slotG)[t];
        acsr[aoff[d4.x * RR + t4.x] + sa.x] = s4.x;
        acsr[aoff[d4.y * RR + t4.y] + sa.y] = s4.y;
        acsr[aoff[d4.z * RR + t4.z] + sa.z] = s4.z;
        acsr[aoff[d4.w * RR + t4.w] + sa.w] = s4.w;
        gcsr[goff[s4.x] + sg.x] = d4.x;
        gcsr[goff[s4.y] + sg.y] = d4.y;
        gcsr[goff[s4.z] + sg.z] = d4.z;
        gcsr[goff[s4.w] + sg.w] = d4.w;
    } else {
        for (int e = e0; e < E; e++) {
            int s0 = src[e], d0 = dst[e];
            acsr[aoff[d0 * RR + et[e]] + slotA[e]] = s0;
            gcsr[goff[s0] + slotG[e]] = d0;
        }
    }
}

// ---------------------------------------------------------------------------
// gate gather: 16-lane group per node, short8 row loads (round-6 measured
// form: 4-wide head + pairwise + scalar tails, plain loads).
// TAUb[n] = bf16(tanh( mean_out (h[n]-h[dst])^2 ))
// ---------------------------------------------------------------------------
__global__ __launch_bounds__(256) void gate_gather(
    const ushort* __restrict__ Hc, const int* __restrict__ gcsr,
    const int* __restrict__ goff, const int* __restrict__ deg,
    ushort* __restrict__ TAUb, int N)
{
    const int g = threadIdx.x >> 4, lane = threadIdx.x & 15;
    const int n = blockIdx.x * 16 + g;
    if (n >= N) return;
    const int start = goff[n];
    const int c = deg[n];
    const ushort* hbase = Hc + lane * 8;
    const short8 a8 = *(const short8*)(hbase + (size_t)n * 128);
    float av[8];
#pragma unroll
    for (int j = 0; j < 8; j++) av[j] = b2f((ushort)a8[j]);
    float acc[8];
#pragma unroll
    for (int j = 0; j < 8; j++) acc[j] = 0.f;

    int i = 0;
    for (; i + 4 <= c; i += 4) {
        int d0 = gcsr[start + i],     d1 = gcsr[start + i + 1];
        int d2 = gcsr[start + i + 2], d3 = gcsr[start + i + 3];
        short8 b0 = *(const short8*)(hbase + (size_t)d0 * 128);
        short8 b1 = *(const short8*)(hbase + (size_t)d1 * 128);
        short8 b2 = *(const short8*)(hbase + (size_t)d2 * 128);
        short8 b3 = *(const short8*)(hbase + (size_t)d3 * 128);
#pragma unroll
        for (int j = 0; j < 8; j++) {
            float dx0 = av[j] - b2f((ushort)b0[j]);
            float dx1 = av[j] - b2f((ushort)b1[j]);
            float dx2 = av[j] - b2f((ushort)b2[j]);
            float dx3 = av[j] - b2f((ushort)b3[j]);
            acc[j] += dx0 * dx0 + dx1 * dx1 + dx2 * dx2 + dx3 * dx3;
        }
    }
    if (i + 2 <= c) {
        int d0 = gcsr[start + i], d1 = gcsr[start + i + 1];
        short8 b0 = *(const short8*)(hbase + (size_t)d0 * 128);
        short8 b1 = *(const short8*)(hbase + (size_t)d1 * 128);
#pragma unroll
        for (int j = 0; j < 8; j++) {
            float dx0 = av[j] - b2f((ushort)b0[j]);
            float dx1 = av[j] - b2f((ushort)b1[j]);
            acc[j] += dx0 * dx0 + dx1 * dx1;
        }
        i += 2;
    }
    if (i < c) {
        int d0 = gcsr[start + i];
        short8 b0 = *(const short8*)(hbase + (size_t)d0 * 128);
#pragma unroll
        for (int j = 0; j < 8; j++) {
            float dx0 = av[j] - b2f((ushort)b0[j]);
            acc[j] += dx0 * dx0;
        }
    }
    const float inv = (c > 0) ? (1.f / (float)c) : 1.f;
    short8 t;
#pragma unroll
    for (int j = 0; j < 8; j++) t[j] = (short)f2b(tanhf(acc[j] * inv));
    *(short8*)(TAUb + (size_t)n * D + lane * 8) = t;
}

// ---------------------------------------------------------------------------
// agg gather, NODE-per-group, 16-lane groups + short8 row loads (round-6
// measured-good form: decoupled 4-wide load stream, cum-reset, NT out stores).
// ---------------------------------------------------------------------------
__global__ __launch_bounds__(256) void agg_gather(
    ushort* __restrict__ Agg, const ushort* __restrict__ Hc,
    const int* __restrict__ acsr, const int* __restrict__ aoff,
    const int* __restrict__ cnt, int N)
{
    const int g = threadIdx.x >> 4, lane = threadIdx.x & 15;
    const int n = blockIdx.x * 16 + g;
    if (n >= N) return;
    const int sbase = n * RR;
    const int start = aoff[sbase];         // node's edges contiguous from here
    int ctot = 0;
#pragma unroll
    for (int r0 = 0; r0 < RR; r0++) ctot += cnt[sbase + r0];   // one hot line

    const ushort* hbase = Hc + lane * 8;
    ushort* obase = Agg + (size_t)n * 1024 + lane * 8;

    float cum[8];
#pragma unroll
    for (int j = 0; j < 8; j++) cum[j] = 0.f;
    int r = 0;
    int segstart = 0;
    int nexte = cnt[sbase];                // end of segment 0

    auto flush = [&]() {
        int c = nexte - segstart;
        short8 outv = {0, 0, 0, 0, 0, 0, 0, 0};
        if (c > 0) {
            float inv = 1.f / (float)c;
#pragma unroll
            for (int j = 0; j < 8; j++) outv[j] = (short)f2b(cum[j] * inv);
        }
        __builtin_nontemporal_store(outv, (short8*)(obase + r * 128));
#pragma unroll
        for (int j = 0; j < 8; j++) cum[j] = 0.f;
        segstart = nexte;
        r++;
        if (r < RR) nexte += cnt[sbase + r];
    };

    int i = 0;
    for (; i + 4 <= ctot; i += 4) {
        int s0 = acsr[start + i],     s1 = acsr[start + i + 1];
        int s2 = acsr[start + i + 2], s3 = acsr[start + i + 3];
        short8 y0 = *(const short8*)(hbase + (size_t)s0 * 128);
        short8 y1 = *(const short8*)(hbase + (size_t)s1 * 128);
        short8 y2 = *(const short8*)(hbase + (size_t)s2 * 128);
        short8 y3 = *(const short8*)(hbase + (size_t)s3 * 128);
        while (i >= nexte) flush();
#pragma unroll
        for (int j = 0; j < 8; j++) cum[j] += b2f((ushort)y0[j]);
        while (i + 1 >= nexte) flush();
#pragma unroll
        for (int j = 0; j < 8; j++) cum[j] += b2f((ushort)y1[j]);
        while (i + 2 >= nexte) flush();
#pragma unroll
        for (int j = 0; j < 8; j++) cum[j] += b2f((ushort)y2[j]);
        while (i + 3 >= nexte) flush();
#pragma unroll
        for (int j = 0; j < 8; j++) cum[j] += b2f((ushort)y3[j]);
    }
    for (; i < ctot; i++) {
        int s0 = acsr[start + i];
        short8 y0 = *(const short8*)(hbase + (size_t)s0 * 128);
        while (i >= nexte) flush();
#pragma unroll
        for (int j = 0; j < 8; j++) cum[j] += b2f((ushort)y0[j]);
    }
    while (r < RR) flush();
}

// ---------------------------------------------------------------------------
// h_next = (1-tau)*h + tau*hn  (hn already relu'd by GEMM epilogue);
// writes fp32 hn and compact bf16 Hc
// ---------------------------------------------------------------------------
__global__ void finalize(const float* __restrict__ hp, float* __restrict__ hn,
                         const ushort* __restrict__ TAUb, ushort* __restrict__ Hc,
                         int total4)
{
    int idx = blockIdx.x * 256 + threadIdx.x;
    if (idx >= total4) return;
    const float4 p = ((const float4*)hp)[idx];
    const float4 a = ((const float4*)hn)[idx];
    const ushort4 t4 = ((const ushort4*)TAUb)[idx];
    float4 o;
    o.x = p.x + b2f(t4.x) * (a.x - p.x);
    o.y = p.y + b2f(t4.y) * (a.y - p.y);
    o.z = p.z + b2f(t4.z) * (a.z - p.z);
    o.w = p.w + b2f(t4.w) * (a.w - p.w);
    ((float4*)hn)[idx] = o;
    ushort4 ob = { f2b(o.x), f2b(o.y), f2b(o.z), f2b(o.w) };
    *(ushort4*)(Hc + (size_t)idx * 4) = ob;
}

// ---------------------------------------------------------------------------
extern "C" void kernel_launch(void* const* d_in, const int* in_sizes, int n_in,
                              void* d_out, int out_size, void* d_ws, size_t ws_size,
                              hipStream_t stream)
{
    const float* x      = (const float*)d_in[0];
    const int*   src    = (const int*)  d_in[1];
    const int*   dst    = (const int*)  d_in[2];
    const int*   etyp   = (const int*)  d_in[3];
    const float* projW  = (const float*)d_in[4];
    const float* projb  = (const float*)d_in[5];
    const float* basis1 = (const float*)d_in[6];
    const float* comp1  = (const float*)d_in[7];
    const float* root1  = (const float*)d_in[8];
    const float* bias1  = (const float*)d_in[9];
    const float* basis2 = (const float*)d_in[10];
    const float* comp2  = (const float*)d_in[11];
    const float* root2  = (const float*)d_in[12];
    const float* bias2  = (const float*)d_in[13];
    const float* outW   = (const float*)d_in[14];
    const float* outb   = (const float*)d_in[15];

    const int N    = in_sizes[0] / D;
    const int E    = in_sizes[1];
    const int OUTD = in_sizes[15];

    float* out  = (float*)d_out;
    float* lat0 = out + (size_t)N * OUTD;
    float* lat1 = lat0 + (size_t)N * D;
    float* lat2 = lat1 + (size_t)N * D;

    // ---- workspace layout ----
    char* p = (char*)d_ws;
    ushort* Agg   = (ushort*)p;  p += (size_t)N * 1024 * 2;   // [N][8*128] bf16
    ushort* Hc    = (ushort*)p;  p += (size_t)N * 128 * 2;    // [N][128] bf16
    ushort* TAUb  = (ushort*)p;  p += (size_t)N * D * 2;
    ushort* projWT = (ushort*)p; p += 16384 * 2;
    ushort* outWT  = (ushort*)p; p += 16384 * 2;
    ushort* bigBT1 = (ushort*)p; p += (size_t)128 * 1152 * 2;
    ushort* bigBT2 = (ushort*)p; p += (size_t)128 * 1152 * 2;
    int* cnt_i  = (int*)p;       p += (size_t)N * RR * 4;
    int* deg_i  = (int*)p;       p += (size_t)N * 4;
    int* aoff   = (int*)p;       p += (size_t)N * RR * 4;
    int* goff   = (int*)p;       p += (size_t)N * 4;
    int* slotA  = (int*)p;       p += (size_t)E * 4;
    int* slotG  = (int*)p;       p += (size_t)E * 4;
    int* acsr   = (int*)p;       p += (size_t)E * 4;
    int* gcsr   = (int*)p;       p += (size_t)E * 4;
    int* bsum   = (int*)p;       p += 4096;

    if ((size_t)(p - (char*)d_ws) > ws_size) return;  // fails loudly

    // zero counters (cnt_i, deg_i contiguous)
    hipMemsetAsync(cnt_i, 0, sizeof(int) * ((size_t)N * RR + N), stream);

    // weight prep
    build_bigBT<<<(128 * 1152 + 255) / 256, 256, 0, stream>>>(basis1, comp1, root1, bigBT1);
    build_bigBT<<<(128 * 1152 + 255) / 256, 256, 0, stream>>>(basis2, comp2, root2, bigBT2);
    transpose_pad<<<64, 256, 0, stream>>>(projW, projWT, 128);
    transpose_pad<<<64, 256, 0, stream>>>(outW, outWT, OUTD);

    cast_x<<<(N * 32 + 255) / 256, 256, 0, stream>>>(x, Hc, N * 32);

    count_slot<<<(E / 4 + 255) / 256, 256, 0, stream>>>(
        src, dst, etyp, cnt_i, deg_i, slotA, slotG, E);

    {   // exclusive scans -> CSR offsets
        int n1 = N * RR, nb1 = (n1 + 1023) / 1024;
        scan1<<<nb1, 256, 0, stream>>>(cnt_i, bsum, n1);
        scan_top<<<1, 1024, 0, stream>>>(bsum, nb1);
        scan2<<<nb1, 256, 0, stream>>>(cnt_i, bsum, aoff, n1);
        int nb2 = (N + 1023) / 1024;
        scan1<<<nb2, 256, 0, stream>>>(deg_i, bsum, N);
        scan_top<<<1, 1024, 0, stream>>>(bsum, nb2);
        scan2<<<nb2, 256, 0, stream>>>(deg_i, bsum, goff, N);
    }

    fill_scatter<<<(E / 4 + 255) / 256, 256, 0, stream>>>(
        src, dst, etyp, aoff, goff, slotA, slotG, acsr, gcsr, E);

    const int mb = (N + 127) / 128;
    const int nodeblocks16 = (N + 15) / 16;

    // proj: lat0 = relu(x @ projW + projb); bf16 -> Hc (in-place safe)
    gemm_bf16<true, true, true, true><<<mb, 256, 0, stream>>>(
        Hc, 128, 2, Hc, 128, projWT, 1, projb, lat0, 128, Hc, 128, N, 128);

    const ushort* bigBT[2] = {bigBT1, bigBT2};
    const float* biases[2] = {bias1, bias2};
    float* lats[3]         = {lat0, lat1, lat2};

    for (int l = 0; l < 2; l++) {
        float* hn = lats[l + 1];

        gate_gather<<<nodeblocks16, 256, 0, stream>>>(Hc, gcsr, goff, deg_i, TAUb, N);
        agg_gather<<<nodeblocks16, 256, 0, stream>>>(Agg, Hc, acsr, aoff, cnt_i, N);

        // hn = relu([Agg | Hc] @ [W_1..W_8; root] + bias)
        gemm_bf16<true, true, true, false><<<mb, 256, 0, stream>>>(
            Agg, 1024, 16, Hc, 128, bigBT[l], 9, biases[l], hn, 128, nullptr, 0, N, 128);

        finalize<<<(N * 32 + 255) / 256, 256, 0, stream>>>(
            lats[l], hn, TAUb, Hc, N * 32);
    }

    // out = lat2 @ outW + outb
    gemm_bf16<true, false, true, false><<<mb, 256, 0, stream>>>(
        Hc, 128, 2, Hc, 128, outWT, 1, outb, out, OUTD, nullptr, 0, N, OUTD);
}

// Round 10
// 998.180 us; speedup vs baseline: 1.2521x; 1.0223x over previous
//
#include <hip/hip_runtime.h>
#include <cstdint>
#include <cstddef>

#define D 128
#define RR 8

typedef __attribute__((ext_vector_type(8))) short short8;
typedef __attribute__((ext_vector_type(4))) float f32x4;

__device__ inline ushort f2b(float x) {
    union { float f; unsigned u; } v; v.f = x;
    unsigned r = v.u + 0x7fff + ((v.u >> 16) & 1);
    return (ushort)(r >> 16);
}
__device__ inline float b2f(ushort u) {
    union { unsigned u; float f; } v; v.u = ((unsigned)u) << 16; return v.f;
}

// async global->LDS, 16B per lane; LDS dest = wave-uniform base + lane*16
__device__ inline void gload_lds16(const ushort* g, ushort* l) {
    __builtin_amdgcn_global_load_lds(
        (const __attribute__((address_space(1))) unsigned int*)g,
        (__attribute__((address_space(3))) unsigned int*)l, 16, 0, 0);
}

// ---------------------------------------------------------------------------
// bf16 MFMA GEMM with SPLIT A: C[M, ncol] = [A0 | A1] @ B (+bias) (+relu)
// GATE variant fuses the gated residual: o = hp + tau*(relu(acc+bias) - hp),
// storing o to Cf (fp32) and Cb (bf16) — deletes the separate finalize pass
// and the hn fp32 round-trip.  In-place A1==Cb safe (block reads its own rows
// in the K-loop before the epilogue writes them; proj validated this).
// ---------------------------------------------------------------------------
template<bool BIAS, bool RELU, bool STF, bool STB, bool GATE>
__global__ __launch_bounds__(256, 4) void gemm_bf16(
    const ushort* __restrict__ A0, int lda0, int k0steps,
    const ushort* __restrict__ A1, int lda1,
    const ushort* __restrict__ BT, int ktiles,
    const float* __restrict__ bias, float* __restrict__ Cf, int ldcf,
    ushort* __restrict__ Cb, int ldcb,
    const float* __restrict__ hp, const ushort* __restrict__ TAU,
    int M, int ncol)
{
    __shared__ ushort As[128 * 64];
    __shared__ ushort Bs[128 * 64];
    const int tid = threadIdx.x;
    const int m0 = blockIdx.x * 128;
    const int ldb = ktiles * 128;
    const int ksteps = ktiles * 2;          // BK = 64

    const int w = tid >> 6, lane = tid & 63;
    const int wm = (w & 1) * 64, wn = (w >> 1) * 64;
    const int l15 = lane & 15, quad = lane >> 4;

    const ushort* a0p[4];
    const ushort* a1p[4];
    const ushort* bp[4];
#pragma unroll
    for (int it = 0; it < 4; it++) {
        int gi = w * 256 + it * 64 + lane;
        int row = gi >> 3, g = gi & 7;
        int cg = g ^ (row & 7);
        int gr = m0 + row; if (gr > M - 1) gr = M - 1;   // clamp tail
        a0p[it] = A0 + (size_t)gr * lda0 + (cg << 3);
        a1p[it] = A1 + (size_t)gr * lda1 + (cg << 3);
        bp[it]  = BT + (size_t)row * ldb + (cg << 3);    // B rows 0..127 always valid
    }

    f32x4 acc[4][4];
    const f32x4 z4 = {0.f, 0.f, 0.f, 0.f};
#pragma unroll
    for (int i = 0; i < 4; i++)
#pragma unroll
        for (int j = 0; j < 4; j++) acc[i][j] = z4;

    for (int kt = 0; kt < ksteps; kt++) {
        const int ko = kt * 64;
        if (kt < k0steps) {
#pragma unroll
            for (int it = 0; it < 4; it++)
                gload_lds16(a0p[it] + ko, As + w * 2048 + it * 512);
        } else {
            const int ko1 = (kt - k0steps) * 64;
#pragma unroll
            for (int it = 0; it < 4; it++)
                gload_lds16(a1p[it] + ko1, As + w * 2048 + it * 512);
        }
#pragma unroll
        for (int it = 0; it < 4; it++)
            gload_lds16(bp[it] + ko, Bs + w * 2048 + it * 512);
        __syncthreads();   // compiler emits vmcnt(0) drain before barrier

#pragma unroll
        for (int ks = 0; ks < 64; ks += 32) {
            const int q0 = (ks >> 3) + quad;        // k-group 0..7
            short8 af[4], bfr[4];
#pragma unroll
            for (int i = 0; i < 4; i++) {
                int row = wm + i * 16 + l15;
                af[i] = *(const short8*)(&As[row * 64 + ((q0 ^ (row & 7)) << 3)]);
            }
#pragma unroll
            for (int j = 0; j < 4; j++) {
                int row = wn + j * 16 + l15;
                bfr[j] = *(const short8*)(&Bs[row * 64 + ((q0 ^ (row & 7)) << 3)]);
            }
#pragma unroll
            for (int i = 0; i < 4; i++)
#pragma unroll
                for (int j = 0; j < 4; j++)
                    acc[i][j] = __builtin_amdgcn_mfma_f32_16x16x32_bf16(
                        af[i], bfr[j], acc[i][j], 0, 0, 0);
        }
        __syncthreads();
    }

    // epilogue: C[m=quad*4+q][n=l15] per 16x16 frag
#pragma unroll
    for (int i = 0; i < 4; i++) {
#pragma unroll
        for (int q = 0; q < 4; q++) {
            int gm = m0 + wm + i * 16 + quad * 4 + q;
            if (gm >= M) continue;
#pragma unroll
            for (int j = 0; j < 4; j++) {
                int gn = wn + j * 16 + l15;
                if (gn >= ncol) continue;
                float v = acc[i][j][q];
                if (BIAS) v += bias[gn];
                if (RELU) v = v > 0.f ? v : 0.f;
                if (GATE) {
                    float pv  = hp[(size_t)gm * 128 + gn];
                    float tau = b2f(TAU[(size_t)gm * 128 + gn]);
                    v = pv + tau * (v - pv);
                }
                if (STF) Cf[(size_t)gm * ldcf + gn] = v;
                if (STB) Cb[(size_t)gm * ldcb + gn] = f2b(v);
            }
        }
    }
}

// ---------------------------------------------------------------------------
// bigBT[f][c]: c<1024 -> W_{c>>7}[c&127][f];  c>=1024 -> root[c-1024][f]
// ---------------------------------------------------------------------------
__global__ void build_bigBT(const float* __restrict__ basis,
                            const float* __restrict__ comp,
                            const float* __restrict__ root,
                            ushort* __restrict__ BT)
{
    int i = blockIdx.x * 256 + threadIdx.x;
    if (i >= 128 * 1152) return;
    int f = i / 1152, c = i - f * 1152;
    float a;
    if (c < 1024) {
        int r = c >> 7, d = c & 127;
        a = 0.f;
#pragma unroll
        for (int b = 0; b < 4; b++)
            a += comp[r * 4 + b] * basis[(b * 128 + d) * 128 + f];
    } else {
        a = root[(c - 1024) * 128 + f];
    }
    BT[i] = f2b(a);
}

// out[f*128+k] = bf16(in[k*cols+f]) for f<cols else 0   (in: [128][cols])
__global__ void transpose_pad(const float* __restrict__ in, ushort* __restrict__ out,
                              int cols)
{
    int i = blockIdx.x * 256 + threadIdx.x;
    if (i >= 128 * 128) return;
    int k = i & 127, f = i >> 7;
    out[i] = (f < cols) ? f2b(in[k * cols + f]) : (ushort)0;
}

// x [N][128] fp32 -> compact bf16 Hc [N][128]
__global__ void cast_x(const float* __restrict__ in, ushort* __restrict__ Hc, int total4)
{
    int i = blockIdx.x * 256 + threadIdx.x;
    if (i >= total4) return;
    float4 v = ((const float4*)in)[i];
    ushort4 o = { f2b(v.x), f2b(v.y), f2b(v.z), f2b(v.w) };
    *(ushort4*)(Hc + (size_t)i * 4) = o;
}

// ---------------------------------------------------------------------------
// count pass recording each edge's slot (atomicAdd return).  int4 loads/stores
// (round-7 measured: 193 -> 138 us; structural atomic floor).
// ---------------------------------------------------------------------------
__global__ void count_slot(const int* __restrict__ src, const int* __restrict__ dst,
                           const int* __restrict__ et, int* __restrict__ cnt,
                           int* __restrict__ deg, int* __restrict__ slotA,
                           int* __restrict__ slotG, int E)
{
    int t = blockIdx.x * 256 + threadIdx.x;
    int e0 = t * 4;
    if (e0 + 4 <= E) {
        int4 s4 = ((const int4*)src)[t];
        int4 d4 = ((const int4*)dst)[t];
        int4 t4 = ((const int4*)et)[t];
        int4 sa, sg;
        sa.x = atomicAdd(&cnt[d4.x * RR + t4.x], 1);
        sa.y = atomicAdd(&cnt[d4.y * RR + t4.y], 1);
        sa.z = atomicAdd(&cnt[d4.z * RR + t4.z], 1);
        sa.w = atomicAdd(&cnt[d4.w * RR + t4.w], 1);
        sg.x = atomicAdd(&deg[s4.x], 1);
        sg.y = atomicAdd(&deg[s4.y], 1);
        sg.z = atomicAdd(&deg[s4.z], 1);
        sg.w = atomicAdd(&deg[s4.w], 1);
        ((int4*)slotA)[t] = sa;
        ((int4*)slotG)[t] = sg;
    } else {
        for (int e = e0; e < E; e++) {
            slotA[e] = atomicAdd(&cnt[dst[e] * RR + et[e]], 1);
            slotG[e] = atomicAdd(&deg[src[e]], 1);
        }
    }
}

// ---------------------------------------------------------------------------
// 3-phase exclusive scan (1024 elements per block)
// ---------------------------------------------------------------------------
__global__ void scan1(const int* __restrict__ in, int* __restrict__ bsum, int n)
{
    __shared__ int s[256];
    const int b = blockIdx.x, t = threadIdx.x;
    const int base = b * 1024;
    int v = 0;
#pragma unroll
    for (int i = 0; i < 4; i++) {
        int idx = base + t * 4 + i;
        if (idx < n) v += in[idx];
    }
    s[t] = v; __syncthreads();
    for (int off = 128; off > 0; off >>= 1) {
        if (t < off) s[t] += s[t + off];
        __syncthreads();
    }
    if (t == 0) bsum[b] = s[0];
}

__global__ void scan_top(int* __restrict__ bsum, int nb)
{
    __shared__ int s[1024];
    const int t = threadIdx.x;
    int v = (t < nb) ? bsum[t] : 0;
    s[t] = v; __syncthreads();
    for (int off = 1; off < 1024; off <<= 1) {
        int x = (t >= off) ? s[t - off] : 0;
        __syncthreads();
        s[t] += x;
        __syncthreads();
    }
    if (t < nb) bsum[t] = s[t] - v;   // exclusive
}

__global__ void scan2(const int* __restrict__ in, const int* __restrict__ bsum,
                      int* __restrict__ out, int n)
{
    __shared__ int s[256];
    const int b = blockIdx.x, t = threadIdx.x;
    const int base = b * 1024;
    int loc[4];
    int v = 0;
#pragma unroll
    for (int i = 0; i < 4; i++) {
        int idx = base + t * 4 + i;
        int x = (idx < n) ? in[idx] : 0;
        loc[i] = v; v += x;
    }
    s[t] = v; __syncthreads();
    for (int off = 1; off < 256; off <<= 1) {
        int x = (t >= off) ? s[t - off] : 0;
        __syncthreads();
        s[t] += x;
        __syncthreads();
    }
    const int add = bsum[b] + (s[t] - v);
#pragma unroll
    for (int i = 0; i < 4; i++) {
        int idx = base + t * 4 + i;
        if (idx < n) out[idx] = add + loc[i];
    }
}

// ---------------------------------------------------------------------------
// fill pass with NO atomics: position = scanned offset + pre-recorded slot.
// ---------------------------------------------------------------------------
__global__ void fill_scatter(const int* __restrict__ src, const int* __restrict__ dst,
                             const int* __restrict__ et,
                             const int* __restrict__ aoff, const int* __restrict__ goff,
                             const int* __restrict__ slotA, const int* __restrict__ slotG,
                             int* __restrict__ acsr, int* __restrict__ gcsr, int E)
{
    int t = blockIdx.x * 256 + threadIdx.x;
    int e0 = t * 4;
    if (e0 + 4 <= E) {
        int4 s4 = ((const int4*)src)[t];
        int4 d4 = ((const int4*)dst)[t];
        int4 t4 = ((const int4*)et)[t];
        int4 sa = ((const int4*)slotA)[t];
        int4 sg = ((const int4*)slotG)[t];
        acsr[aoff[d4.x * RR + t4.x] + sa.x] = s4.x;
        acsr[aoff[d4.y * RR + t4.y] + sa.y] = s4.y;
        acsr[aoff[d4.z * RR + t4.z] + sa.z] = s4.z;
        acsr[aoff[d4.w * RR + t4.w] + sa.w] = s4.w;
        gcsr[goff[s4.x] + sg.x] = d4.x;
        gcsr[goff[s4.y] + sg.y] = d4.y;
        gcsr[goff[s4.z] + sg.z] = d4.z;
        gcsr[goff[s4.w] + sg.w] = d4.w;
    } else {
        for (int e = e0; e < E; e++) {
            int s0 = src[e], d0 = dst[e];
            acsr[aoff[d0 * RR + et[e]] + slotA[e]] = s0;
            gcsr[goff[s0] + slotG[e]] = d0;
        }
    }
}

// ---------------------------------------------------------------------------
// MERGED gathers: blocks [0, nbA) run agg (longer), blocks [nbA, 2*nbA) run
// gate.  Both latency-bound at ~78% occupancy individually — co-residency
// fills each other's memory-stall bubbles and removes serialization.
// Bodies are the round-6/9 measured-good forms, verbatim.
// ---------------------------------------------------------------------------
__global__ __launch_bounds__(256) void gathers(
    ushort* __restrict__ Agg, const ushort* __restrict__ Hc,
    const int* __restrict__ acsr, const int* __restrict__ aoff,
    const int* __restrict__ cnt,
    const int* __restrict__ gcsr, const int* __restrict__ goff,
    const int* __restrict__ deg, ushort* __restrict__ TAUb,
    int N, int nbA)
{
    const int g = threadIdx.x >> 4, lane = threadIdx.x & 15;
    if (blockIdx.x < nbA) {
        // ----- agg: node-per-group, decoupled 4-wide stream, cum-reset -----
        const int n = blockIdx.x * 16 + g;
        if (n >= N) return;
        const int sbase = n * RR;
        const int start = aoff[sbase];
        int ctot = 0;
#pragma unroll
        for (int r0 = 0; r0 < RR; r0++) ctot += cnt[sbase + r0];

        const ushort* hbase = Hc + lane * 8;
        ushort* obase = Agg + (size_t)n * 1024 + lane * 8;

        float cum[8];
#pragma unroll
        for (int j = 0; j < 8; j++) cum[j] = 0.f;
        int r = 0;
        int segstart = 0;
        int nexte = cnt[sbase];

        auto flush = [&]() {
            int c = nexte - segstart;
            short8 outv = {0, 0, 0, 0, 0, 0, 0, 0};
            if (c > 0) {
                float inv = 1.f / (float)c;
#pragma unroll
                for (int j = 0; j < 8; j++) outv[j] = (short)f2b(cum[j] * inv);
            }
            __builtin_nontemporal_store(outv, (short8*)(obase + r * 128));
#pragma unroll
            for (int j = 0; j < 8; j++) cum[j] = 0.f;
            segstart = nexte;
            r++;
            if (r < RR) nexte += cnt[sbase + r];
        };

        int i = 0;
        for (; i + 4 <= ctot; i += 4) {
            int s0 = acsr[start + i],     s1 = acsr[start + i + 1];
            int s2 = acsr[start + i + 2], s3 = acsr[start + i + 3];
            short8 y0 = *(const short8*)(hbase + (size_t)s0 * 128);
            short8 y1 = *(const short8*)(hbase + (size_t)s1 * 128);
            short8 y2 = *(const short8*)(hbase + (size_t)s2 * 128);
            short8 y3 = *(const short8*)(hbase + (size_t)s3 * 128);
            while (i >= nexte) flush();
#pragma unroll
            for (int j = 0; j < 8; j++) cum[j] += b2f((ushort)y0[j]);
            while (i + 1 >= nexte) flush();
#pragma unroll
            for (int j = 0; j < 8; j++) cum[j] += b2f((ushort)y1[j]);
            while (i + 2 >= nexte) flush();
#pragma unroll
            for (int j = 0; j < 8; j++) cum[j] += b2f((ushort)y2[j]);
            while (i + 3 >= nexte) flush();
#pragma unroll
            for (int j = 0; j < 8; j++) cum[j] += b2f((ushort)y3[j]);
        }
        for (; i < ctot; i++) {
            int s0 = acsr[start + i];
            short8 y0 = *(const short8*)(hbase + (size_t)s0 * 128);
            while (i >= nexte) flush();
#pragma unroll
            for (int j = 0; j < 8; j++) cum[j] += b2f((ushort)y0[j]);
        }
        while (r < RR) flush();
    } else {
        // ----- gate: 4-wide head + pairwise + scalar tail -----
        const int n = (blockIdx.x - nbA) * 16 + g;
        if (n >= N) return;
        const int start = goff[n];
        const int c = deg[n];
        const ushort* hbase = Hc + lane * 8;
        const short8 a8 = *(const short8*)(hbase + (size_t)n * 128);
        float av[8];
#pragma unroll
        for (int j = 0; j < 8; j++) av[j] = b2f((ushort)a8[j]);
        float acc[8];
#pragma unroll
        for (int j = 0; j < 8; j++) acc[j] = 0.f;

        int i = 0;
        for (; i + 4 <= c; i += 4) {
            int d0 = gcsr[start + i],     d1 = gcsr[start + i + 1];
            int d2 = gcsr[start + i + 2], d3 = gcsr[start + i + 3];
            short8 b0 = *(const short8*)(hbase + (size_t)d0 * 128);
            short8 b1 = *(const short8*)(hbase + (size_t)d1 * 128);
            short8 b2 = *(const short8*)(hbase + (size_t)d2 * 128);
            short8 b3 = *(const short8*)(hbase + (size_t)d3 * 128);
#pragma unroll
            for (int j = 0; j < 8; j++) {
                float dx0 = av[j] - b2f((ushort)b0[j]);
                float dx1 = av[j] - b2f((ushort)b1[j]);
                float dx2 = av[j] - b2f((ushort)b2[j]);
                float dx3 = av[j] - b2f((ushort)b3[j]);
                acc[j] += dx0 * dx0 + dx1 * dx1 + dx2 * dx2 + dx3 * dx3;
            }
        }
        if (i + 2 <= c) {
            int d0 = gcsr[start + i], d1 = gcsr[start + i + 1];
            short8 b0 = *(const short8*)(hbase + (size_t)d0 * 128);
            short8 b1 = *(const short8*)(hbase + (size_t)d1 * 128);
#pragma unroll
            for (int j = 0; j < 8; j++) {
                float dx0 = av[j] - b2f((ushort)b0[j]);
                float dx1 = av[j] - b2f((ushort)b1[j]);
                acc[j] += dx0 * dx0 + dx1 * dx1;
            }
            i += 2;
        }
        if (i < c) {
            int d0 = gcsr[start + i];
            short8 b0 = *(const short8*)(hbase + (size_t)d0 * 128);
#pragma unroll
            for (int j = 0; j < 8; j++) {
                float dx0 = av[j] - b2f((ushort)b0[j]);
                acc[j] += dx0 * dx0;
            }
        }
        const float inv = (c > 0) ? (1.f / (float)c) : 1.f;
        short8 t;
#pragma unroll
        for (int j = 0; j < 8; j++) t[j] = (short)f2b(tanhf(acc[j] * inv));
        *(short8*)(TAUb + (size_t)n * D + lane * 8) = t;
    }
}

// ---------------------------------------------------------------------------
extern "C" void kernel_launch(void* const* d_in, const int* in_sizes, int n_in,
                              void* d_out, int out_size, void* d_ws, size_t ws_size,
                              hipStream_t stream)
{
    const float* x      = (const float*)d_in[0];
    const int*   src    = (const int*)  d_in[1];
    const int*   dst    = (const int*)  d_in[2];
    const int*   etyp   = (const int*)  d_in[3];
    const float* projW  = (const float*)d_in[4];
    const float* projb  = (const float*)d_in[5];
    const float* basis1 = (const float*)d_in[6];
    const float* comp1  = (const float*)d_in[7];
    const float* root1  = (const float*)d_in[8];
    const float* bias1  = (const float*)d_in[9];
    const float* basis2 = (const float*)d_in[10];
    const float* comp2  = (const float*)d_in[11];
    const float* root2  = (const float*)d_in[12];
    const float* bias2  = (const float*)d_in[13];
    const float* outW   = (const float*)d_in[14];
    const float* outb   = (const float*)d_in[15];

    const int N    = in_sizes[0] / D;
    const int E    = in_sizes[1];
    const int OUTD = in_sizes[15];

    float* out  = (float*)d_out;
    float* lat0 = out + (size_t)N * OUTD;
    float* lat1 = lat0 + (size_t)N * D;
    float* lat2 = lat1 + (size_t)N * D;

    // ---- workspace layout ----
    char* p = (char*)d_ws;
    ushort* Agg   = (ushort*)p;  p += (size_t)N * 1024 * 2;   // [N][8*128] bf16
    ushort* Hc    = (ushort*)p;  p += (size_t)N * 128 * 2;    // [N][128] bf16
    ushort* TAUb  = (ushort*)p;  p += (size_t)N * D * 2;
    ushort* projWT = (ushort*)p; p += 16384 * 2;
    ushort* outWT  = (ushort*)p; p += 16384 * 2;
    ushort* bigBT1 = (ushort*)p; p += (size_t)128 * 1152 * 2;
    ushort* bigBT2 = (ushort*)p; p += (size_t)128 * 1152 * 2;
    int* cnt_i  = (int*)p;       p += (size_t)N * RR * 4;
    int* deg_i  = (int*)p;       p += (size_t)N * 4;
    int* aoff   = (int*)p;       p += (size_t)N * RR * 4;
    int* goff   = (int*)p;       p += (size_t)N * 4;
    int* slotA  = (int*)p;       p += (size_t)E * 4;
    int* slotG  = (int*)p;       p += (size_t)E * 4;
    int* acsr   = (int*)p;       p += (size_t)E * 4;
    int* gcsr   = (int*)p;       p += (size_t)E * 4;
    int* bsum   = (int*)p;       p += 4096;

    if ((size_t)(p - (char*)d_ws) > ws_size) return;  // fails loudly

    // zero counters (cnt_i, deg_i contiguous)
    hipMemsetAsync(cnt_i, 0, sizeof(int) * ((size_t)N * RR + N), stream);

    // weight prep
    build_bigBT<<<(128 * 1152 + 255) / 256, 256, 0, stream>>>(basis1, comp1, root1, bigBT1);
    build_bigBT<<<(128 * 1152 + 255) / 256, 256, 0, stream>>>(basis2, comp2, root2, bigBT2);
    transpose_pad<<<64, 256, 0, stream>>>(projW, projWT, 128);
    transpose_pad<<<64, 256, 0, stream>>>(outW, outWT, OUTD);

    cast_x<<<(N * 32 + 255) / 256, 256, 0, stream>>>(x, Hc, N * 32);

    count_slot<<<(E / 4 + 255) / 256, 256, 0, stream>>>(
        src, dst, etyp, cnt_i, deg_i, slotA, slotG, E);

    {   // exclusive scans -> CSR offsets
        int n1 = N * RR, nb1 = (n1 + 1023) / 1024;
        scan1<<<nb1, 256, 0, stream>>>(cnt_i, bsum, n1);
        scan_top<<<1, 1024, 0, stream>>>(bsum, nb1);
        scan2<<<nb1, 256, 0, stream>>>(cnt_i, bsum, aoff, n1);
        int nb2 = (N + 1023) / 1024;
        scan1<<<nb2, 256, 0, stream>>>(deg_i, bsum, N);
        scan_top<<<1, 1024, 0, stream>>>(bsum, nb2);
        scan2<<<nb2, 256, 0, stream>>>(deg_i, bsum, goff, N);
    }

    fill_scatter<<<(E / 4 + 255) / 256, 256, 0, stream>>>(
        src, dst, etyp, aoff, goff, slotA, slotG, acsr, gcsr, E);

    const int mb = (N + 127) / 128;
    const int nbA = (N + 15) / 16;

    // proj: lat0 = relu(x @ projW + projb); bf16 -> Hc (in-place safe)
    gemm_bf16<true, true, true, true, false><<<mb, 256, 0, stream>>>(
        Hc, 128, 2, Hc, 128, projWT, 1, projb, lat0, 128, Hc, 128,
        nullptr, nullptr, N, 128);

    const ushort* bigBT[2] = {bigBT1, bigBT2};
    const float* biases[2] = {bias1, bias2};
    float* lats[3]         = {lat0, lat1, lat2};

    for (int l = 0; l < 2; l++) {
        float* hn = lats[l + 1];

        // merged agg + gate (concurrent block ranges; agg first — longer)
        gathers<<<2 * nbA, 256, 0, stream>>>(
            Agg, Hc, acsr, aoff, cnt_i, gcsr, goff, deg_i, TAUb, N, nbA);

        // hn = hp + tau*(relu([Agg|Hc]@bigBT + bias) - hp); also bf16 -> Hc
        gemm_bf16<true, true, true, true, true><<<mb, 256, 0, stream>>>(
            Agg, 1024, 16, Hc, 128, bigBT[l], 9, biases[l], hn, 128, Hc, 128,
            lats[l], TAUb, N, 128);
    }

    // out = lat2 @ outW + outb
    gemm_bf16<true, false, true, false, false><<<mb, 256, 0, stream>>>(
        Hc, 128, 2, Hc, 128, outWT, 1, outb, out, OUTD, nullptr, 0,
        nullptr, nullptr, N, OUTD);
}

// Round 11
// 979.085 us; speedup vs baseline: 1.2765x; 1.0195x over previous
//
#include <hip/hip_runtime.h>
#include <cstdint>
#include <cstddef>

#define D 128
#define RR 8

typedef __attribute__((ext_vector_type(8))) short short8;
typedef __attribute__((ext_vector_type(4))) float f32x4;

__device__ inline ushort f2b(float x) {
    union { float f; unsigned u; } v; v.f = x;
    unsigned r = v.u + 0x7fff + ((v.u >> 16) & 1);
    return (ushort)(r >> 16);
}
__device__ inline float b2f(ushort u) {
    union { unsigned u; float f; } v; v.u = ((unsigned)u) << 16; return v.f;
}

// async global->LDS, 16B per lane; LDS dest = wave-uniform base + lane*16
__device__ inline void gload_lds16(const ushort* g, ushort* l) {
    __builtin_amdgcn_global_load_lds(
        (const __attribute__((address_space(1))) unsigned int*)g,
        (__attribute__((address_space(3))) unsigned int*)l, 16, 0, 0);
}

// ---------------------------------------------------------------------------
// GEMM body (device fn): C[M, ncol] = [A0 | A1] @ B (+bias) (+relu) (+gate)
// Identical to the round-10 measured-good kernel body; As/Bs passed from the
// calling kernel's __shared__ (128*64 ushort each).
// ---------------------------------------------------------------------------
template<bool BIAS, bool RELU, bool STF, bool STB, bool GATE>
__device__ inline void gemm_body(
    ushort* As, ushort* Bs, int blk,
    const ushort* __restrict__ A0, int lda0, int k0steps,
    const ushort* __restrict__ A1, int lda1,
    const ushort* __restrict__ BT, int ktiles,
    const float* __restrict__ bias, float* __restrict__ Cf, int ldcf,
    ushort* __restrict__ Cb, int ldcb,
    const float* __restrict__ hp, const ushort* __restrict__ TAU,
    int M, int ncol)
{
    const int tid = threadIdx.x;
    const int m0 = blk * 128;
    const int ldb = ktiles * 128;
    const int ksteps = ktiles * 2;          // BK = 64

    const int w = tid >> 6, lane = tid & 63;
    const int wm = (w & 1) * 64, wn = (w >> 1) * 64;
    const int l15 = lane & 15, quad = lane >> 4;

    const ushort* a0p[4];
    const ushort* a1p[4];
    const ushort* bp[4];
#pragma unroll
    for (int it = 0; it < 4; it++) {
        int gi = w * 256 + it * 64 + lane;
        int row = gi >> 3, g = gi & 7;
        int cg = g ^ (row & 7);
        int gr = m0 + row; if (gr > M - 1) gr = M - 1;   // clamp tail
        a0p[it] = A0 + (size_t)gr * lda0 + (cg << 3);
        a1p[it] = A1 + (size_t)gr * lda1 + (cg << 3);
        bp[it]  = BT + (size_t)row * ldb + (cg << 3);    // B rows 0..127 always valid
    }

    f32x4 acc[4][4];
    const f32x4 z4 = {0.f, 0.f, 0.f, 0.f};
#pragma unroll
    for (int i = 0; i < 4; i++)
#pragma unroll
        for (int j = 0; j < 4; j++) acc[i][j] = z4;

    for (int kt = 0; kt < ksteps; kt++) {
        const int ko = kt * 64;
        if (kt < k0steps) {
#pragma unroll
            for (int it = 0; it < 4; it++)
                gload_lds16(a0p[it] + ko, As + w * 2048 + it * 512);
        } else {
            const int ko1 = (kt - k0steps) * 64;
#pragma unroll
            for (int it = 0; it < 4; it++)
                gload_lds16(a1p[it] + ko1, As + w * 2048 + it * 512);
        }
#pragma unroll
        for (int it = 0; it < 4; it++)
            gload_lds16(bp[it] + ko, Bs + w * 2048 + it * 512);
        __syncthreads();   // compiler emits vmcnt(0) drain before barrier

#pragma unroll
        for (int ks = 0; ks < 64; ks += 32) {
            const int q0 = (ks >> 3) + quad;        // k-group 0..7
            short8 af[4], bfr[4];
#pragma unroll
            for (int i = 0; i < 4; i++) {
                int row = wm + i * 16 + l15;
                af[i] = *(const short8*)(&As[row * 64 + ((q0 ^ (row & 7)) << 3)]);
            }
#pragma unroll
            for (int j = 0; j < 4; j++) {
                int row = wn + j * 16 + l15;
                bfr[j] = *(const short8*)(&Bs[row * 64 + ((q0 ^ (row & 7)) << 3)]);
            }
#pragma unroll
            for (int i = 0; i < 4; i++)
#pragma unroll
                for (int j = 0; j < 4; j++)
                    acc[i][j] = __builtin_amdgcn_mfma_f32_16x16x32_bf16(
                        af[i], bfr[j], acc[i][j], 0, 0, 0);
        }
        __syncthreads();
    }

    // epilogue: C[m=quad*4+q][n=l15] per 16x16 frag
#pragma unroll
    for (int i = 0; i < 4; i++) {
#pragma unroll
        for (int q = 0; q < 4; q++) {
            int gm = m0 + wm + i * 16 + quad * 4 + q;
            if (gm >= M) continue;
#pragma unroll
            for (int j = 0; j < 4; j++) {
                int gn = wn + j * 16 + l15;
                if (gn >= ncol) continue;
                float v = acc[i][j][q];
                if (BIAS) v += bias[gn];
                if (RELU) v = v > 0.f ? v : 0.f;
                if (GATE) {
                    float pv  = hp[(size_t)gm * 128 + gn];
                    float tau = b2f(TAU[(size_t)gm * 128 + gn]);
                    v = pv + tau * (v - pv);
                }
                if (STF) Cf[(size_t)gm * ldcf + gn] = v;
                if (STB) Cb[(size_t)gm * ldcb + gn] = f2b(v);
            }
        }
    }
}

template<bool BIAS, bool RELU, bool STF, bool STB, bool GATE>
__global__ __launch_bounds__(256, 4) void gemm_bf16(
    const ushort* __restrict__ A0, int lda0, int k0steps,
    const ushort* __restrict__ A1, int lda1,
    const ushort* __restrict__ BT, int ktiles,
    const float* __restrict__ bias, float* __restrict__ Cf, int ldcf,
    ushort* __restrict__ Cb, int ldcb,
    const float* __restrict__ hp, const ushort* __restrict__ TAU,
    int M, int ncol)
{
    __shared__ ushort As[128 * 64];
    __shared__ ushort Bs[128 * 64];
    gemm_body<BIAS, RELU, STF, STB, GATE>(As, Bs, blockIdx.x,
        A0, lda0, k0steps, A1, lda1, BT, ktiles, bias, Cf, ldcf,
        Cb, ldcb, hp, TAU, M, ncol);
}

// ---------------------------------------------------------------------------
// count_slot body: records each edge's slot (atomicAdd return), int4 form.
// ---------------------------------------------------------------------------
__device__ inline void count_body(
    const int* __restrict__ src, const int* __restrict__ dst,
    const int* __restrict__ et, int* __restrict__ cnt,
    int* __restrict__ deg, int* __restrict__ slotA,
    int* __restrict__ slotG, int E, int t)
{
    int e0 = t * 4;
    if (e0 + 4 <= E) {
        int4 s4 = ((const int4*)src)[t];
        int4 d4 = ((const int4*)dst)[t];
        int4 t4 = ((const int4*)et)[t];
        int4 sa, sg;
        sa.x = atomicAdd(&cnt[d4.x * RR + t4.x], 1);
        sa.y = atomicAdd(&cnt[d4.y * RR + t4.y], 1);
        sa.z = atomicAdd(&cnt[d4.z * RR + t4.z], 1);
        sa.w = atomicAdd(&cnt[d4.w * RR + t4.w], 1);
        sg.x = atomicAdd(&deg[s4.x], 1);
        sg.y = atomicAdd(&deg[s4.y], 1);
        sg.z = atomicAdd(&deg[s4.z], 1);
        sg.w = atomicAdd(&deg[s4.w], 1);
        ((int4*)slotA)[t] = sa;
        ((int4*)slotG)[t] = sg;
    } else {
        for (int e = e0; e < E; e++) {
            slotA[e] = atomicAdd(&cnt[dst[e] * RR + et[e]], 1);
            slotG[e] = atomicAdd(&deg[src[e]], 1);
        }
    }
}

// ---------------------------------------------------------------------------
// MERGED proj GEMM + count_slot: disjoint resources (MFMA vs atomics), no
// data dependency.  Blocks [0,mb) = proj; [mb, mb+cb) = count.
// ---------------------------------------------------------------------------
__global__ __launch_bounds__(256, 4) void proj_count(
    ushort* __restrict__ Hc, const ushort* __restrict__ projWT,
    const float* __restrict__ projb, float* __restrict__ lat0, int M,
    const int* __restrict__ src, const int* __restrict__ dst,
    const int* __restrict__ et, int* __restrict__ cnt, int* __restrict__ deg,
    int* __restrict__ slotA, int* __restrict__ slotG, int E, int mb)
{
    __shared__ ushort As[128 * 64];
    __shared__ ushort Bs[128 * 64];
    if ((int)blockIdx.x < mb) {
        gemm_body<true, true, true, true, false>(As, Bs, blockIdx.x,
            Hc, 128, 2, Hc, 128, projWT, 1, projb, lat0, 128, Hc, 128,
            nullptr, nullptr, M, 128);
    } else {
        count_body(src, dst, et, cnt, deg, slotA, slotG, E,
                   (blockIdx.x - mb) * 256 + threadIdx.x);
    }
}

// ---------------------------------------------------------------------------
// MERGED prep: cast_x | build_bigBT1 | build_bigBT2 | transpose projWT | outWT
// ---------------------------------------------------------------------------
__device__ inline void bigBT_body(const float* __restrict__ basis,
                                  const float* __restrict__ comp,
                                  const float* __restrict__ root,
                                  ushort* __restrict__ BT, int i)
{
    if (i >= 128 * 1152) return;
    int f = i / 1152, c = i - f * 1152;
    float a;
    if (c < 1024) {
        int r = c >> 7, d = c & 127;
        a = 0.f;
#pragma unroll
        for (int b = 0; b < 4; b++)
            a += comp[r * 4 + b] * basis[(b * 128 + d) * 128 + f];
    } else {
        a = root[(c - 1024) * 128 + f];
    }
    BT[i] = f2b(a);
}

__device__ inline void transpose_body(const float* __restrict__ in,
                                      ushort* __restrict__ out, int cols, int i)
{
    if (i >= 128 * 128) return;
    int k = i & 127, f = i >> 7;
    out[i] = (f < cols) ? f2b(in[k * cols + f]) : (ushort)0;
}

__global__ void prep(
    const float* __restrict__ x, ushort* __restrict__ Hc, int total4, int nbCast,
    const float* __restrict__ basis1, const float* __restrict__ comp1,
    const float* __restrict__ root1, ushort* __restrict__ BT1,
    const float* __restrict__ basis2, const float* __restrict__ comp2,
    const float* __restrict__ root2, ushort* __restrict__ BT2, int nbBig,
    const float* __restrict__ projW, ushort* __restrict__ projWT,
    const float* __restrict__ outW, ushort* __restrict__ outWT, int OUTD)
{
    int b = blockIdx.x, tid = threadIdx.x;
    if (b < nbCast) {
        int i = b * 256 + tid;
        if (i < total4) {
            float4 v = ((const float4*)x)[i];
            ushort4 o = { f2b(v.x), f2b(v.y), f2b(v.z), f2b(v.w) };
            *(ushort4*)(Hc + (size_t)i * 4) = o;
        }
        return;
    }
    b -= nbCast;
    if (b < nbBig) { bigBT_body(basis1, comp1, root1, BT1, b * 256 + tid); return; }
    b -= nbBig;
    if (b < nbBig) { bigBT_body(basis2, comp2, root2, BT2, b * 256 + tid); return; }
    b -= nbBig;
    if (b < 64) { transpose_body(projW, projWT, 128, b * 256 + tid); return; }
    b -= 64;
    transpose_body(outW, outWT, OUTD, b * 256 + tid);
}

// ---------------------------------------------------------------------------
// merged 3-phase exclusive scans (A-chain: n elems; G-chain: n elems)
// ---------------------------------------------------------------------------
__device__ inline void scan1_body(int* s, const int* __restrict__ in,
                                  int* __restrict__ bsum, int n, int b)
{
    const int t = threadIdx.x;
    const int base = b * 1024;
    int v = 0;
#pragma unroll
    for (int i = 0; i < 4; i++) {
        int idx = base + t * 4 + i;
        if (idx < n) v += in[idx];
    }
    s[t] = v; __syncthreads();
    for (int off = 128; off > 0; off >>= 1) {
        if (t < off) s[t] += s[t + off];
        __syncthreads();
    }
    if (t == 0) bsum[b] = s[0];
}

__device__ inline void scan2_body(int* s, const int* __restrict__ in,
                                  const int* __restrict__ bsum,
                                  int* __restrict__ out, int n, int b)
{
    const int t = threadIdx.x;
    const int base = b * 1024;
    int loc[4];
    int v = 0;
#pragma unroll
    for (int i = 0; i < 4; i++) {
        int idx = base + t * 4 + i;
        int x = (idx < n) ? in[idx] : 0;
        loc[i] = v; v += x;
    }
    s[t] = v; __syncthreads();
    for (int off = 1; off < 256; off <<= 1) {
        int x = (t >= off) ? s[t - off] : 0;
        __syncthreads();
        s[t] += x;
        __syncthreads();
    }
    const int add = bsum[b] + (s[t] - v);
#pragma unroll
    for (int i = 0; i < 4; i++) {
        int idx = base + t * 4 + i;
        if (idx < n) out[idx] = add + loc[i];
    }
}

__global__ void scan1m(const int* __restrict__ inA, int* __restrict__ bsumA,
                       int nA, int nbA,
                       const int* __restrict__ inG, int* __restrict__ bsumG, int nG)
{
    __shared__ int s[256];
    if ((int)blockIdx.x < nbA) scan1_body(s, inA, bsumA, nA, blockIdx.x);
    else                       scan1_body(s, inG, bsumG, nG, blockIdx.x - nbA);
}

__global__ void scan_top2(int* __restrict__ bsumA, int nb1,
                          int* __restrict__ bsumG, int nb2)
{
    __shared__ int s[1024];
    int* bsum = (blockIdx.x == 0) ? bsumA : bsumG;
    int nb    = (blockIdx.x == 0) ? nb1 : nb2;
    const int t = threadIdx.x;
    int v = (t < nb) ? bsum[t] : 0;
    s[t] = v; __syncthreads();
    for (int off = 1; off < 1024; off <<= 1) {
        int x = (t >= off) ? s[t - off] : 0;
        __syncthreads();
        s[t] += x;
        __syncthreads();
    }
    if (t < nb) bsum[t] = s[t] - v;   // exclusive
}

__global__ void scan2m(const int* __restrict__ inA, const int* __restrict__ bsumA,
                       int* __restrict__ outA, int nA, int nbA,
                       const int* __restrict__ inG, const int* __restrict__ bsumG,
                       int* __restrict__ outG, int nG)
{
    __shared__ int s[256];
    if ((int)blockIdx.x < nbA) scan2_body(s, inA, bsumA, outA, nA, blockIdx.x);
    else                       scan2_body(s, inG, bsumG, outG, nG, blockIdx.x - nbA);
}

// ---------------------------------------------------------------------------
// fill pass with NO atomics: position = scanned offset + pre-recorded slot.
// ---------------------------------------------------------------------------
__global__ void fill_scatter(const int* __restrict__ src, const int* __restrict__ dst,
                             const int* __restrict__ et,
                             const int* __restrict__ aoff, const int* __restrict__ goff,
                             const int* __restrict__ slotA, const int* __restrict__ slotG,
                             int* __restrict__ acsr, int* __restrict__ gcsr, int E)
{
    int t = blockIdx.x * 256 + threadIdx.x;
    int e0 = t * 4;
    if (e0 + 4 <= E) {
        int4 s4 = ((const int4*)src)[t];
        int4 d4 = ((const int4*)dst)[t];
        int4 t4 = ((const int4*)et)[t];
        int4 sa = ((const int4*)slotA)[t];
        int4 sg = ((const int4*)slotG)[t];
        acsr[aoff[d4.x * RR + t4.x] + sa.x] = s4.x;
        acsr[aoff[d4.y * RR + t4.y] + sa.y] = s4.y;
        acsr[aoff[d4.z * RR + t4.z] + sa.z] = s4.z;
        acsr[aoff[d4.w * RR + t4.w] + sa.w] = s4.w;
        gcsr[goff[s4.x] + sg.x] = d4.x;
        gcsr[goff[s4.y] + sg.y] = d4.y;
        gcsr[goff[s4.z] + sg.z] = d4.z;
        gcsr[goff[s4.w] + sg.w] = d4.w;
    } else {
        for (int e = e0; e < E; e++) {
            int s0 = src[e], d0 = dst[e];
            acsr[aoff[d0 * RR + et[e]] + slotA[e]] = s0;
            gcsr[goff[s0] + slotG[e]] = d0;
        }
    }
}

// ---------------------------------------------------------------------------
// MERGED gathers (round-10 measured-good, verbatim): blocks [0,nbA) = agg,
// [nbA, 2*nbA) = gate.
// ---------------------------------------------------------------------------
__global__ __launch_bounds__(256) void gathers(
    ushort* __restrict__ Agg, const ushort* __restrict__ Hc,
    const int* __restrict__ acsr, const int* __restrict__ aoff,
    const int* __restrict__ cnt,
    const int* __restrict__ gcsr, const int* __restrict__ goff,
    const int* __restrict__ deg, ushort* __restrict__ TAUb,
    int N, int nbA)
{
    const int g = threadIdx.x >> 4, lane = threadIdx.x & 15;
    if ((int)blockIdx.x < nbA) {
        const int n = blockIdx.x * 16 + g;
        if (n >= N) return;
        const int sbase = n * RR;
        const int start = aoff[sbase];
        int ctot = 0;
#pragma unroll
        for (int r0 = 0; r0 < RR; r0++) ctot += cnt[sbase + r0];

        const ushort* hbase = Hc + lane * 8;
        ushort* obase = Agg + (size_t)n * 1024 + lane * 8;

        float cum[8];
#pragma unroll
        for (int j = 0; j < 8; j++) cum[j] = 0.f;
        int r = 0;
        int segstart = 0;
        int nexte = cnt[sbase];

        auto flush = [&]() {
            int c = nexte - segstart;
            short8 outv = {0, 0, 0, 0, 0, 0, 0, 0};
            if (c > 0) {
                float inv = 1.f / (float)c;
#pragma unroll
                for (int j = 0; j < 8; j++) outv[j] = (short)f2b(cum[j] * inv);
            }
            __builtin_nontemporal_store(outv, (short8*)(obase + r * 128));
#pragma unroll
            for (int j = 0; j < 8; j++) cum[j] = 0.f;
            segstart = nexte;
            r++;
            if (r < RR) nexte += cnt[sbase + r];
        };

        int i = 0;
        for (; i + 4 <= ctot; i += 4) {
            int s0 = acsr[start + i],     s1 = acsr[start + i + 1];
            int s2 = acsr[start + i + 2], s3 = acsr[start + i + 3];
            short8 y0 = *(const short8*)(hbase + (size_t)s0 * 128);
            short8 y1 = *(const short8*)(hbase + (size_t)s1 * 128);
            short8 y2 = *(const short8*)(hbase + (size_t)s2 * 128);
            short8 y3 = *(const short8*)(hbase + (size_t)s3 * 128);
            while (i >= nexte) flush();
#pragma unroll
            for (int j = 0; j < 8; j++) cum[j] += b2f((ushort)y0[j]);
            while (i + 1 >= nexte) flush();
#pragma unroll
            for (int j = 0; j < 8; j++) cum[j] += b2f((ushort)y1[j]);
            while (i + 2 >= nexte) flush();
#pragma unroll
            for (int j = 0; j < 8; j++) cum[j] += b2f((ushort)y2[j]);
            while (i + 3 >= nexte) flush();
#pragma unroll
            for (int j = 0; j < 8; j++) cum[j] += b2f((ushort)y3[j]);
        }
        for (; i < ctot; i++) {
            int s0 = acsr[start + i];
            short8 y0 = *(const short8*)(hbase + (size_t)s0 * 128);
            while (i >= nexte) flush();
#pragma unroll
            for (int j = 0; j < 8; j++) cum[j] += b2f((ushort)y0[j]);
        }
        while (r < RR) flush();
    } else {
        const int n = (blockIdx.x - nbA) * 16 + g;
        if (n >= N) return;
        const int start = goff[n];
        const int c = deg[n];
        const ushort* hbase = Hc + lane * 8;
        const short8 a8 = *(const short8*)(hbase + (size_t)n * 128);
        float av[8];
#pragma unroll
        for (int j = 0; j < 8; j++) av[j] = b2f((ushort)a8[j]);
        float acc[8];
#pragma unroll
        for (int j = 0; j < 8; j++) acc[j] = 0.f;

        int i = 0;
        for (; i + 4 <= c; i += 4) {
            int d0 = gcsr[start + i],     d1 = gcsr[start + i + 1];
            int d2 = gcsr[start + i + 2], d3 = gcsr[start + i + 3];
            short8 b0 = *(const short8*)(hbase + (size_t)d0 * 128);
            short8 b1 = *(const short8*)(hbase + (size_t)d1 * 128);
            short8 b2 = *(const short8*)(hbase + (size_t)d2 * 128);
            short8 b3 = *(const short8*)(hbase + (size_t)d3 * 128);
#pragma unroll
            for (int j = 0; j < 8; j++) {
                float dx0 = av[j] - b2f((ushort)b0[j]);
                float dx1 = av[j] - b2f((ushort)b1[j]);
                float dx2 = av[j] - b2f((ushort)b2[j]);
                float dx3 = av[j] - b2f((ushort)b3[j]);
                acc[j] += dx0 * dx0 + dx1 * dx1 + dx2 * dx2 + dx3 * dx3;
            }
        }
        if (i + 2 <= c) {
            int d0 = gcsr[start + i], d1 = gcsr[start + i + 1];
            short8 b0 = *(const short8*)(hbase + (size_t)d0 * 128);
            short8 b1 = *(const short8*)(hbase + (size_t)d1 * 128);
#pragma unroll
            for (int j = 0; j < 8; j++) {
                float dx0 = av[j] - b2f((ushort)b0[j]);
                float dx1 = av[j] - b2f((ushort)b1[j]);
                acc[j] += dx0 * dx0 + dx1 * dx1;
            }
            i += 2;
        }
        if (i < c) {
            int d0 = gcsr[start + i];
            short8 b0 = *(const short8*)(hbase + (size_t)d0 * 128);
#pragma unroll
            for (int j = 0; j < 8; j++) {
                float dx0 = av[j] - b2f((ushort)b0[j]);
                acc[j] += dx0 * dx0;
            }
        }
        const float inv = (c > 0) ? (1.f / (float)c) : 1.f;
        short8 t;
#pragma unroll
        for (int j = 0; j < 8; j++) t[j] = (short)f2b(tanhf(acc[j] * inv));
        *(short8*)(TAUb + (size_t)n * D + lane * 8) = t;
    }
}

// ---------------------------------------------------------------------------
extern "C" void kernel_launch(void* const* d_in, const int* in_sizes, int n_in,
                              void* d_out, int out_size, void* d_ws, size_t ws_size,
                              hipStream_t stream)
{
    const float* x      = (const float*)d_in[0];
    const int*   src    = (const int*)  d_in[1];
    const int*   dst    = (const int*)  d_in[2];
    const int*   etyp   = (const int*)  d_in[3];
    const float* projW  = (const float*)d_in[4];
    const float* projb  = (const float*)d_in[5];
    const float* basis1 = (const float*)d_in[6];
    const float* comp1  = (const float*)d_in[7];
    const float* root1  = (const float*)d_in[8];
    const float* bias1  = (const float*)d_in[9];
    const float* basis2 = (const float*)d_in[10];
    const float* comp2  = (const float*)d_in[11];
    const float* root2  = (const float*)d_in[12];
    const float* bias2  = (const float*)d_in[13];
    const float* outW   = (const float*)d_in[14];
    const float* outb   = (const float*)d_in[15];

    const int N    = in_sizes[0] / D;
    const int E    = in_sizes[1];
    const int OUTD = in_sizes[15];

    float* out  = (float*)d_out;
    float* lat0 = out + (size_t)N * OUTD;
    float* lat1 = lat0 + (size_t)N * D;
    float* lat2 = lat1 + (size_t)N * D;

    // ---- workspace layout ----
    char* p = (char*)d_ws;
    ushort* Agg   = (ushort*)p;  p += (size_t)N * 1024 * 2;   // [N][8*128] bf16
    ushort* Hc    = (ushort*)p;  p += (size_t)N * 128 * 2;    // [N][128] bf16
    ushort* TAUb  = (ushort*)p;  p += (size_t)N * D * 2;
    ushort* projWT = (ushort*)p; p += 16384 * 2;
    ushort* outWT  = (ushort*)p; p += 16384 * 2;
    ushort* bigBT1 = (ushort*)p; p += (size_t)128 * 1152 * 2;
    ushort* bigBT2 = (ushort*)p; p += (size_t)128 * 1152 * 2;
    int* cnt_i  = (int*)p;       p += (size_t)N * RR * 4;
    int* deg_i  = (int*)p;       p += (size_t)N * 4;
    int* aoff   = (int*)p;       p += (size_t)N * RR * 4;
    int* goff   = (int*)p;       p += (size_t)N * 4;
    int* slotA  = (int*)p;       p += (size_t)E * 4;
    int* slotG  = (int*)p;       p += (size_t)E * 4;
    int* acsr   = (int*)p;       p += (size_t)E * 4;
    int* gcsr   = (int*)p;       p += (size_t)E * 4;
    int* bsumA  = (int*)p;       p += 4096;
    int* bsumG  = (int*)p;       p += 4096;

    if ((size_t)(p - (char*)d_ws) > ws_size) return;  // fails loudly

    // zero counters (cnt_i, deg_i contiguous)
    hipMemsetAsync(cnt_i, 0, sizeof(int) * ((size_t)N * RR + N), stream);

    const int mb  = (N + 127) / 128;
    const int nbA = (N + 15) / 16;
    const int nbCast = (N * 32 + 255) / 256;
    const int nbBig  = (128 * 1152 + 255) / 256;
    const int cb  = (E / 4 + 255) / 256;

    // prep: cast_x | bigBT1 | bigBT2 | projWT | outWT  (one launch)
    prep<<<nbCast + 2 * nbBig + 64 + 64, 256, 0, stream>>>(
        x, Hc, N * 32, nbCast,
        basis1, comp1, root1, bigBT1,
        basis2, comp2, root2, bigBT2, nbBig,
        projW, projWT, outW, outWT, OUTD);

    // merged proj GEMM (needs Hc from prep) + count_slot (independent)
    proj_count<<<mb + cb, 256, 0, stream>>>(
        Hc, projWT, projb, lat0, N,
        src, dst, etyp, cnt_i, deg_i, slotA, slotG, E, mb);

    {   // merged exclusive scans -> CSR offsets
        int n1 = N * RR, nb1 = (n1 + 1023) / 1024;
        int nb2 = (N + 1023) / 1024;
        scan1m<<<nb1 + nb2, 256, 0, stream>>>(cnt_i, bsumA, n1, nb1, deg_i, bsumG, N);
        scan_top2<<<2, 1024, 0, stream>>>(bsumA, nb1, bsumG, nb2);
        scan2m<<<nb1 + nb2, 256, 0, stream>>>(cnt_i, bsumA, aoff, n1, nb1,
                                              deg_i, bsumG, goff, N);
    }

    fill_scatter<<<cb, 256, 0, stream>>>(
        src, dst, etyp, aoff, goff, slotA, slotG, acsr, gcsr, E);

    const ushort* bigBT[2] = {bigBT1, bigBT2};
    const float* biases[2] = {bias1, bias2};
    float* lats[3]         = {lat0, lat1, lat2};

    for (int l = 0; l < 2; l++) {
        float* hn = lats[l + 1];

        // merged agg + gate (concurrent block ranges; agg first — longer)
        gathers<<<2 * nbA, 256, 0, stream>>>(
            Agg, Hc, acsr, aoff, cnt_i, gcsr, goff, deg_i, TAUb, N, nbA);

        // hn = hp + tau*(relu([Agg|Hc]@bigBT + bias) - hp); also bf16 -> Hc
        gemm_bf16<true, true, true, true, true><<<mb, 256, 0, stream>>>(
            Agg, 1024, 16, Hc, 128, bigBT[l], 9, biases[l], hn, 128, Hc, 128,
            lats[l], TAUb, N, 128);
    }

    // out = lat2 @ outW + outb
    gemm_bf16<true, false, true, false, false><<<mb, 256, 0, stream>>>(
        Hc, 128, 2, Hc, 128, outWT, 1, outb, out, OUTD, nullptr, 0,
        nullptr, nullptr, N, OUTD);
}